// Round 10
// baseline (839.440 us; speedup 1.0000x reference)
//
#include <hip/hip_runtime.h>
#include <math.h>

#define D_MODEL  2048
#define D_INNER  2048
#define N_QK     32
#define N_V      32
#define D_STATE  64
#define D_CONV   4
#define CHUNK    128
#define CONV_DIM 6144      // D_INNER + 2*N_QK*D_STATE
#define IN_OUT   8224      // 2*D_INNER + 2*N_QK*D_STATE + N_V
#define BATCH    2
#define SEQ      4096
#define M_ROWS   (BATCH*SEQ)   // 8192
#define NCHUNK   (SEQ/CHUNK)   // 32

typedef unsigned short bf16_t;
typedef __attribute__((ext_vector_type(4))) float f32x4;
typedef __attribute__((ext_vector_type(8))) short bf16x8;

// swizzled row-major LDS index (elem units); XOR bits 3-5 spread rows over banks
#define SWZ64(r,c)  ((((r)*64)  + (c)) ^ (((r)&7)<<3))
#define SWZ128(r,c) ((((r)*128) + (c)) ^ (((r)&7)<<3))

__device__ __forceinline__ float b2f(bf16_t u) {
    union { unsigned int i; float f; } w; w.i = ((unsigned int)u) << 16; return w.f;
}
__device__ __forceinline__ bf16_t f2b(float f) {
    unsigned int x = __float_as_uint(f);
    return (bf16_t)((x + 0x7FFFu + ((x >> 16) & 1u)) >> 16);   // RNE
}
__device__ __forceinline__ void store4b(bf16_t* dst, float4 v) {
    ushort4 u; u.x = f2b(v.x); u.y = f2b(v.y); u.z = f2b(v.z); u.w = f2b(v.w);
    *reinterpret_cast<ushort4*>(dst) = u;
}

__device__ __forceinline__ void gload_lds16(const bf16_t* g, bf16_t* l) {
    __builtin_amdgcn_global_load_lds((const __attribute__((address_space(1))) void*)g,
                                     (__attribute__((address_space(3))) void*)l,
                                     16, 0, 0);
}

// ---------------------------------------------------------------------------
// fp32 -> bf16 convert
// ---------------------------------------------------------------------------
__global__ __launch_bounds__(256) void f2b_kernel(const float* __restrict__ in,
                                                  bf16_t* __restrict__ out, long n)
{
    const long i = ((long)blockIdx.x * 256 + threadIdx.x) * 4;
    if (i < n) {
        float4 v = *reinterpret_cast<const float4*>(in + i);
        ushort4 o;
        o.x = f2b(v.x); o.y = f2b(v.y); o.z = f2b(v.z); o.w = f2b(v.w);
        *reinterpret_cast<ushort4*>(out + i) = o;
    }
}

// ---------------------------------------------------------------------------
// 256x256 bf16 MFMA NT-GEMM, K-half counted-vmcnt pipeline (R9-proven).
// BNMAJOR: wg decomposed bn-major so each XCD chunk keeps its B panels
// L2-resident (gemm1: B=33MB streams otherwise; A streams once).
// M is always 8192 (32 M-tiles).
// ---------------------------------------------------------------------------
template<int NTB, int K, bool OBF16, bool BNMAJOR>
__global__ __launch_bounds__(512, 2) void gemm256(const bf16_t* __restrict__ A,
                                                  const bf16_t* __restrict__ B,
                                                  void* __restrict__ Cv,
                                                  long ldc)
{
    constexpr int BK = 64;
    constexpr int NT = K / BK;
    __shared__ bf16_t As[2][2][8192];   // [buf][kh][1024 slots * 8 elems]
    __shared__ bf16_t Bs[2][2][8192];

    const int nwg = gridDim.x;
    const int bid = blockIdx.x;
    const int wg  = ((nwg & 7) == 0) ? ((bid & 7) * (nwg >> 3) + (bid >> 3)) : bid;
    int bm, bn;
    if (BNMAJOR) { bm = (wg & 31) * 256; bn = (wg >> 5) * 256; }   // M_ROWS/256 == 32
    else         { bm = (wg / NTB) * 256; bn = (wg % NTB) * 256; }

    const int tid  = threadIdx.x;
    const int lane = tid & 63;
    const int wv   = tid >> 6;
    const int wr   = wv >> 2, wc = wv & 3;       // 2x4 wave grid
    const int l15  = lane & 15, l4 = lane >> 4;

    f32x4 acc[8][4];
    #pragma unroll
    for (int i = 0; i < 8; ++i)
        #pragma unroll
        for (int j = 0; j < 4; ++j) acc[i][j] = (f32x4){0.f, 0.f, 0.f, 0.f};

    const bf16_t* Abase = A + (long)bm * K;
    const bf16_t* Bbase = B + (long)bn * K;

    auto stage_half = [&](int t, int buf, int kh) {
        #pragma unroll
        for (int it = 0; it < 2; ++it) {
            const int s   = it * 512 + tid;          // 0..1023
            const int row = s >> 2;                  // 0..255
            const int jp  = s & 3;                   // physical chunk in half
            const int jl  = jp ^ ((row >> 1) & 3);   // logical chunk in half
            const long go = (long)row * K + t * BK + kh * 32 + jl * 8;
            gload_lds16(Abase + go, &As[buf][kh][s * 8]);
            gload_lds16(Bbase + go, &Bs[buf][kh][s * 8]);
        }
    };
    auto rdA = [&](int buf, int kh, int row) {
        const int jp = l4 ^ ((row >> 1) & 3);
        return *reinterpret_cast<const bf16x8*>(&As[buf][kh][(row * 4 + jp) * 8]);
    };
    auto rdB = [&](int buf, int kh, int row) {
        const int jp = l4 ^ ((row >> 1) & 3);
        return *reinterpret_cast<const bf16x8*>(&Bs[buf][kh][(row * 4 + jp) * 8]);
    };

    stage_half(0, 0, 0);
    stage_half(0, 0, 1);
    asm volatile("s_waitcnt vmcnt(4)" ::: "memory");   // K-half0 of tile 0 landed
    __builtin_amdgcn_s_barrier();

    for (int t = 0; t < NT; ++t) {
        const int cur = t & 1;
        bf16x8 bfr[4], af[4];
        if (t + 1 < NT) stage_half(t + 1, cur ^ 1, 0);
        // P1: ks=0, qm=0
        #pragma unroll
        for (int ni = 0; ni < 4; ++ni) bfr[ni] = rdB(cur, 0, wc * 64 + ni * 16 + l15);
        #pragma unroll
        for (int mi = 0; mi < 4; ++mi) af[mi] = rdA(cur, 0, wr * 128 + mi * 16 + l15);
        __builtin_amdgcn_s_setprio(1);
        #pragma unroll
        for (int mi = 0; mi < 4; ++mi)
            #pragma unroll
            for (int ni = 0; ni < 4; ++ni)
                acc[mi][ni] = __builtin_amdgcn_mfma_f32_16x16x32_bf16(
                    af[mi], bfr[ni], acc[mi][ni], 0, 0, 0);
        __builtin_amdgcn_s_setprio(0);
        __builtin_amdgcn_s_barrier();
        // P2: ks=0, qm=1
        #pragma unroll
        for (int mi = 0; mi < 4; ++mi) af[mi] = rdA(cur, 0, wr * 128 + 64 + mi * 16 + l15);
        __builtin_amdgcn_s_setprio(1);
        #pragma unroll
        for (int mi = 0; mi < 4; ++mi)
            #pragma unroll
            for (int ni = 0; ni < 4; ++ni)
                acc[4 + mi][ni] = __builtin_amdgcn_mfma_f32_16x16x32_bf16(
                    af[mi], bfr[ni], acc[4 + mi][ni], 0, 0, 0);
        __builtin_amdgcn_s_setprio(0);
        if (t + 1 < NT) {
            stage_half(t + 1, cur ^ 1, 1);
            asm volatile("s_waitcnt vmcnt(8)" ::: "memory");   // K1(t) landed
        } else {
            asm volatile("s_waitcnt vmcnt(0)" ::: "memory");
        }
        __builtin_amdgcn_s_barrier();
        // P3: ks=1, qm=0
        #pragma unroll
        for (int ni = 0; ni < 4; ++ni) bfr[ni] = rdB(cur, 1, wc * 64 + ni * 16 + l15);
        #pragma unroll
        for (int mi = 0; mi < 4; ++mi) af[mi] = rdA(cur, 1, wr * 128 + mi * 16 + l15);
        __builtin_amdgcn_s_setprio(1);
        #pragma unroll
        for (int mi = 0; mi < 4; ++mi)
            #pragma unroll
            for (int ni = 0; ni < 4; ++ni)
                acc[mi][ni] = __builtin_amdgcn_mfma_f32_16x16x32_bf16(
                    af[mi], bfr[ni], acc[mi][ni], 0, 0, 0);
        __builtin_amdgcn_s_setprio(0);
        __builtin_amdgcn_s_barrier();
        // P4: ks=1, qm=1
        #pragma unroll
        for (int mi = 0; mi < 4; ++mi) af[mi] = rdA(cur, 1, wr * 128 + 64 + mi * 16 + l15);
        __builtin_amdgcn_s_setprio(1);
        #pragma unroll
        for (int mi = 0; mi < 4; ++mi)
            #pragma unroll
            for (int ni = 0; ni < 4; ++ni)
                acc[4 + mi][ni] = __builtin_amdgcn_mfma_f32_16x16x32_bf16(
                    af[mi], bfr[ni], acc[4 + mi][ni], 0, 0, 0);
        __builtin_amdgcn_s_setprio(0);
        if (t + 1 < NT) { asm volatile("s_waitcnt vmcnt(4)" ::: "memory"); }
        __builtin_amdgcn_s_barrier();
    }

    #pragma unroll
    for (int mf = 0; mf < 8; ++mf) {
        const long grow0 = bm + wr * 128 + mf * 16 + l4 * 4;
        #pragma unroll
        for (int ni = 0; ni < 4; ++ni) {
            const int gcol = bn + wc * 64 + ni * 16 + l15;
            #pragma unroll
            for (int j = 0; j < 4; ++j) {
                if (OBF16)
                    ((bf16_t*)Cv)[(grow0 + j) * ldc + gcol] = f2b(acc[mf][ni][j]);
                else
                    ((float*)Cv)[(grow0 + j) * ldc + gcol] = acc[mf][ni][j];
            }
        }
    }
}

// ---------------------------------------------------------------------------
// 128x128 m97-style MFMA GEMM (A_log 32-col tail), ldc-param.
// ---------------------------------------------------------------------------
template<int N, int K, bool OBF16>
__global__ __launch_bounds__(256) void gemm_mfma(const bf16_t* __restrict__ A,
                                                 const bf16_t* __restrict__ B,
                                                 void* __restrict__ Cv,
                                                 long ldc)
{
    constexpr int BM = 128, BN = 128, BK = 64;
    constexpr int NTB = (N + BN - 1) / BN;
    __shared__ bf16_t As[BM * BK];
    __shared__ bf16_t Bs[BM * BK];

    const int nwg = gridDim.x;
    const int bid = blockIdx.x;
    const int wg  = ((nwg & 7) == 0) ? ((bid & 7) * (nwg >> 3) + (bid >> 3)) : bid;
    const int bm = (wg / NTB) * BM;
    const int bn = (wg % NTB) * BN;

    const int tid  = threadIdx.x;
    const int lane = tid & 63;
    const int wv   = tid >> 6;
    const int wr   = wv >> 1, wc = wv & 1;

    f32x4 acc[4][4];
    #pragma unroll
    for (int i = 0; i < 4; ++i)
        #pragma unroll
        for (int j = 0; j < 4; ++j) acc[i][j] = (f32x4){0.f, 0.f, 0.f, 0.f};

    for (int k0 = 0; k0 < K; k0 += BK) {
        #pragma unroll
        for (int it = 0; it < 4; ++it) {
            const int seg = it * 256 + tid;
            const int row = seg >> 3, c16 = seg & 7;
            gload_lds16(A + (long)(bm + row) * K + k0 + c16 * 8,
                        &As[row * BK + c16 * 8]);
            int brow = bn + row;
            if constexpr (N % BN != 0) brow = min(brow, N - 1);
            gload_lds16(B + (long)brow * K + k0 + c16 * 8,
                        &Bs[row * BK + c16 * 8]);
        }
        __syncthreads();
        #pragma unroll
        for (int kk = 0; kk < 2; ++kk) {
            bf16x8 af[4], bfr[4];
            const int kc = kk * 32 + (lane >> 4) * 8;
            #pragma unroll
            for (int mi = 0; mi < 4; ++mi) {
                const int row = wr * 64 + mi * 16 + (lane & 15);
                af[mi] = *reinterpret_cast<const bf16x8*>(&As[row * BK + kc]);
            }
            #pragma unroll
            for (int ni = 0; ni < 4; ++ni) {
                const int row = wc * 64 + ni * 16 + (lane & 15);
                bfr[ni] = *reinterpret_cast<const bf16x8*>(&Bs[row * BK + kc]);
            }
            #pragma unroll
            for (int mi = 0; mi < 4; ++mi)
                #pragma unroll
                for (int ni = 0; ni < 4; ++ni)
                    acc[mi][ni] = __builtin_amdgcn_mfma_f32_16x16x32_bf16(
                        af[mi], bfr[ni], acc[mi][ni], 0, 0, 0);
        }
        __syncthreads();
    }

    #pragma unroll
    for (int mi = 0; mi < 4; ++mi) {
        const long row0 = bm + wr * 64 + mi * 16 + ((lane >> 4) << 2);
        #pragma unroll
        for (int ni = 0; ni < 4; ++ni) {
            const int col = bn + wc * 64 + ni * 16 + (lane & 15);
            if (N % BN != 0 && col >= N) continue;
            #pragma unroll
            for (int j = 0; j < 4; ++j) {
                if (OBF16)
                    ((bf16_t*)Cv)[(row0 + j) * ldc + col] = f2b(acc[mi][ni][j]);
                else
                    ((float*)Cv)[(row0 + j) * ldc + col] = acc[mi][ni][j];
            }
        }
    }
}

// ---------------------------------------------------------------------------
// Fused causal depthwise conv (K=4), 4 consecutive columns, reading bf16 xBCzA.
// ---------------------------------------------------------------------------
__device__ __forceinline__ float4 conv4v(const bf16_t* __restrict__ xb, long m, int l,
                                         int col, const float* __restrict__ cw,
                                         const float* __restrict__ cbv)
{
    float4 acc = *reinterpret_cast<const float4*>(cbv + col);
    float4 wc0 = *reinterpret_cast<const float4*>(cw + (long)col * 4);
    float4 wc1 = *reinterpret_cast<const float4*>(cw + (long)col * 4 + 4);
    float4 wc2 = *reinterpret_cast<const float4*>(cw + (long)col * 4 + 8);
    float4 wc3 = *reinterpret_cast<const float4*>(cw + (long)col * 4 + 12);
    const float t0[4] = {wc0.x, wc0.y, wc0.z, wc0.w};
    const float t1[4] = {wc1.x, wc1.y, wc1.z, wc1.w};
    const float t2[4] = {wc2.x, wc2.y, wc2.z, wc2.w};
    const float t3[4] = {wc3.x, wc3.y, wc3.z, wc3.w};
    #pragma unroll
    for (int tap = 0; tap < 4; ++tap) {
        if (l - 3 + tap < 0) continue;
        const bf16_t* p = xb + (m - 3 + tap) * (long)IN_OUT + col;
        ushort4 v = *reinterpret_cast<const ushort4*>(p);
        acc.x = fmaf(b2f(v.x), t0[tap], acc.x);
        acc.y = fmaf(b2f(v.y), t1[tap], acc.y);
        acc.z = fmaf(b2f(v.z), t2[tap], acc.z);
        acc.w = fmaf(b2f(v.w), t3[tap], acc.w);
    }
    return acc;
}

// ---------------------------------------------------------------------------
// Phase A (MFMA): dt=softplus (self), wave-shuffle cumsum, states via MFMA.
// states stored bf16 in SWZ64-physical order (so ssd_out can gload_lds it
// linearly and ds_read with the same XOR -- rule #21 both-sides form).
// ---------------------------------------------------------------------------
__global__ __launch_bounds__(256) void ssd_states(const bf16_t* __restrict__ xb,
                                                  const float* __restrict__ cw,
                                                  const float* __restrict__ cbv,
                                                  bf16_t* __restrict__ states,
                                                  float* __restrict__ cumbuf,
                                                  float* __restrict__ cdecay)
{
    const int h = blockIdx.x, c = blockIdx.y, b = blockIdx.z;
    __shared__ bf16_t sx [128 * 64];
    __shared__ bf16_t sBr[128 * 64];
    __shared__ bf16_t sXT[64 * 128];
    __shared__ bf16_t sBT[64 * 128];
    __shared__ float  cum[CHUNK];
    __shared__ float  w0tot;
    const int t = threadIdx.x;
    const long mbase = (long)b * SEQ + (long)c * CHUNK;
    const long cb = ((long)b * NCHUNK + c) * N_QK + h;

    // softplus + wave-level inclusive scan (6 shfl steps, no barriers)
    float v = 0.f;
    if (t < CHUNK) {
        const float a = b2f(xb[(mbase + t) * (long)IN_OUT + (CONV_DIM + D_INNER) + h]);
        v = -((a > 20.f) ? a : log1pf(expf(a)));
        #pragma unroll
        for (int s = 1; s < 64; s <<= 1) {
            const float u2 = __shfl_up(v, s, 64);
            if ((t & 63) >= s) v += u2;
        }
        if (t == 63) w0tot = v;
    }
    for (int idx = t; idx < CHUNK * 16; idx += 256) {
        const int k = idx >> 4, q4 = (idx & 15) * 4;
        const long m = mbase + k;
        const int l = (int)(m & (SEQ - 1));
        float4 xv = conv4v(xb, m, l, h * 64 + q4, cw, cbv);
        float4 bv = conv4v(xb, m, l, D_INNER + h * 64 + q4, cw, cbv);
        store4b(&sx [SWZ64(k, q4)], xv);
        store4b(&sBr[SWZ64(k, q4)], bv);
    }
    __syncthreads();
    if (t >= 64 && t < CHUNK) v += w0tot;
    if (t < CHUNK) cum[t] = v;
    __syncthreads();
    const float clast = cum[CHUNK - 1];
    // transpose x -> sXT; B*decay -> sBT
    {
        const int j = t & 127;
        const int c8b = (t >> 7) * 4;
        const float ej = __expf(clast - cum[j]);
        #pragma unroll
        for (int it = 0; it < 4; ++it) {
            const int c8 = c8b + it;
            bf16x8 xv = *reinterpret_cast<const bf16x8*>(&sx [SWZ64(j, c8 * 8)]);
            bf16x8 bv = *reinterpret_cast<const bf16x8*>(&sBr[SWZ64(j, c8 * 8)]);
            #pragma unroll
            for (int e = 0; e < 8; ++e) {
                sXT[SWZ128(c8 * 8 + e, j)] = xv[e];
                sBT[SWZ128(c8 * 8 + e, j)] = f2b(b2f((bf16_t)bv[e]) * ej);
            }
        }
    }
    __syncthreads();

    const int lane = t & 63, wv = t >> 6;
    const int l15 = lane & 15, l4 = lane >> 4;
    f32x4 acc[4];
    #pragma unroll
    for (int nj = 0; nj < 4; ++nj) acc[nj] = (f32x4){0.f, 0.f, 0.f, 0.f};
    #pragma unroll
    for (int ks = 0; ks < 4; ++ks) {
        const int kc = ks * 32 + l4 * 8;
        bf16x8 af = *reinterpret_cast<const bf16x8*>(&sXT[SWZ128(wv * 16 + l15, kc)]);
        #pragma unroll
        for (int nj = 0; nj < 4; ++nj) {
            bf16x8 bf = *reinterpret_cast<const bf16x8*>(&sBT[SWZ128(nj * 16 + l15, kc)]);
            acc[nj] = __builtin_amdgcn_mfma_f32_16x16x32_bf16(af, bf, acc[nj], 0, 0, 0);
        }
    }
    // write bf16, SWZ64-physical within the 4096-elem block
    #pragma unroll
    for (int nj = 0; nj < 4; ++nj) {
        #pragma unroll
        for (int jj = 0; jj < 4; ++jj) {
            const int p = wv * 16 + l4 * 4 + jj;
            states[cb * 4096 + SWZ64(p, nj * 16 + l15)] = f2b(acc[nj][jj]);
        }
    }
    if (t < CHUNK) cumbuf[cb * CHUNK + t] = cum[t];
    if (t == 0)   cdecay[cb] = __expf(clast);
}

// ---------------------------------------------------------------------------
// Phase B: sequential inter-chunk scan over bf16 states (carry in f32).
// Elementwise at fixed physical offset -> SWZ64 layout is preserved.
// 256 blocks = (b,h) x 4 quarters.
// ---------------------------------------------------------------------------
__global__ __launch_bounds__(256) void ssd_scan(bf16_t* __restrict__ states,
                                                const float* __restrict__ cdecay)
{
    const int bid = blockIdx.x;
    const int bh = bid >> 2, q = bid & 3;
    const int b = bh >> 5, h = bh & 31;
    const int t = threadIdx.x;
    const int off = q * 1024 + t * 4;
    float4 carry = make_float4(0.f, 0.f, 0.f, 0.f);
    for (int c = 0; c < NCHUNK; ++c) {
        const long cb = ((long)b * NCHUNK + c) * N_QK + h;
        bf16_t* p = states + cb * 4096 + off;
        const float cd = cdecay[cb];
        ushort4 su = *reinterpret_cast<const ushort4*>(p);
        ushort4 pv;
        pv.x = f2b(carry.x); pv.y = f2b(carry.y);
        pv.z = f2b(carry.z); pv.w = f2b(carry.w);
        *reinterpret_cast<ushort4*>(p) = pv;
        carry.x = fmaf(carry.x, cd, b2f(su.x));
        carry.y = fmaf(carry.y, cd, b2f(su.y));
        carry.z = fmaf(carry.z, cd, b2f(su.z));
        carry.w = fmaf(carry.w, cd, b2f(su.w));
    }
}

// ---------------------------------------------------------------------------
// Phase C (MFMA): S=C·B^T (tri+decay) -> Q bf16 -> y = Q·x + e·(C·prev^T) + D·x
// gate silu(z+zb) -> yz bf16. prev staged via direct global_load_lds (bf16,
// already SWZ64-physical). 4 waves, wave-private Q, no inner barriers.
// ---------------------------------------------------------------------------
__global__ __launch_bounds__(256) void ssd_out(const bf16_t* __restrict__ xb,
                                               const float* __restrict__ cumbuf,
                                               const bf16_t* __restrict__ prevst,
                                               const float* __restrict__ Dvec,
                                               const float* __restrict__ zbias,
                                               const float* __restrict__ cw,
                                               const float* __restrict__ cbv,
                                               bf16_t* __restrict__ yz)
{
    const int h = blockIdx.x, c = blockIdx.y, b = blockIdx.z;
    __shared__ bf16_t sC[128 * 64];
    __shared__ bf16_t sB[128 * 64];
    __shared__ bf16_t sXQ[128 * 64];   // x tile, later aliased as Q
    __shared__ bf16_t sXT[64 * 128];   // x^T
    __shared__ bf16_t sP[64 * 64];     // prev state (bf16, SWZ64-physical)
    __shared__ float  cum[CHUNK];
    const int t = threadIdx.x;
    const long mbase = (long)b * SEQ + (long)c * CHUNK;
    const long cb = ((long)b * NCHUNK + c) * N_QK + h;
    if (t < CHUNK) cum[t] = cumbuf[cb * CHUNK + t];
    // prev: direct linear copy (global already SWZ64-physical)
    #pragma unroll
    for (int it = 0; it < 2; ++it) {
        const int s = it * 256 + t;             // 512 slots of 16B
        gload_lds16(prevst + cb * 4096 + s * 8, &sP[s * 8]);
    }
    for (int idx = t; idx < CHUNK * 16; idx += 256) {
        const int k = idx >> 4, q4 = (idx & 15) * 4;
        const long m = mbase + k;
        const int l = (int)(m & (SEQ - 1));
        float4 xv = conv4v(xb, m, l, h * 64 + q4, cw, cbv);
        float4 bv = conv4v(xb, m, l, D_INNER + h * 64 + q4, cw, cbv);
        float4 cv = conv4v(xb, m, l, 2 * D_INNER + h * 64 + q4, cw, cbv);
        store4b(&sXQ[SWZ64(k, q4)], xv);
        store4b(&sB [SWZ64(k, q4)], bv);
        store4b(&sC [SWZ64(k, q4)], cv);
    }
    __syncthreads();
    {
        const int j = t & 127;
        const int c8b = (t >> 7) * 4;
        #pragma unroll
        for (int it = 0; it < 4; ++it) {
            const int c8 = c8b + it;
            bf16x8 v = *reinterpret_cast<const bf16x8*>(&sXQ[SWZ64(j, c8 * 8)]);
            #pragma unroll
            for (int e = 0; e < 8; ++e) sXT[SWZ128(c8 * 8 + e, j)] = v[e];
        }
    }
    __syncthreads();   // sXQ now dead as x; becomes wave-private Q

    const int lane = t & 63, wv = t >> 6;
    const int w32 = wv * 32, l15 = lane & 15, l4 = lane >> 4;
    bf16_t* sQ = sXQ;

    f32x4 yac[2][4], iac[2][4];
    #pragma unroll
    for (int mi = 0; mi < 2; ++mi)
        #pragma unroll
        for (int np = 0; np < 4; ++np) {
            yac[mi][np] = (f32x4){0.f, 0.f, 0.f, 0.f};
            iac[mi][np] = (f32x4){0.f, 0.f, 0.f, 0.f};
        }

    #pragma unroll
    for (int H = 0; H < 2; ++H) {
        if (H == 1 && wv < 2) break;
        const int j0 = H * 64;
        f32x4 sac[2][4];
        #pragma unroll
        for (int mi = 0; mi < 2; ++mi)
            #pragma unroll
            for (int nj = 0; nj < 4; ++nj) sac[mi][nj] = (f32x4){0.f, 0.f, 0.f, 0.f};
        #pragma unroll
        for (int kk = 0; kk < 2; ++kk) {
            const int kc = kk * 32 + l4 * 8;
            bf16x8 af0 = *reinterpret_cast<const bf16x8*>(&sC[SWZ64(w32 + l15, kc)]);
            bf16x8 af1 = *reinterpret_cast<const bf16x8*>(&sC[SWZ64(w32 + 16 + l15, kc)]);
            #pragma unroll
            for (int nj = 0; nj < 4; ++nj) {
                bf16x8 bfj = *reinterpret_cast<const bf16x8*>(&sB[SWZ64(j0 + nj * 16 + l15, kc)]);
                if (j0 + nj * 16 <= w32 + 15)
                    sac[0][nj] = __builtin_amdgcn_mfma_f32_16x16x32_bf16(af0, bfj, sac[0][nj], 0, 0, 0);
                if (j0 + nj * 16 <= w32 + 31)
                    sac[1][nj] = __builtin_amdgcn_mfma_f32_16x16x32_bf16(af1, bfj, sac[1][nj], 0, 0, 0);
            }
        }
        #pragma unroll
        for (int mi = 0; mi < 2; ++mi) {
            #pragma unroll
            for (int nj = 0; nj < 4; ++nj) {
                const int jcol = nj * 16 + l15;
                const int jg = j0 + jcol;
                #pragma unroll
                for (int jj = 0; jj < 4; ++jj) {
                    const int i = w32 + mi * 16 + l4 * 4 + jj;
                    const float q = (jg <= i) ? __expf(cum[i] - cum[jg]) * sac[mi][nj][jj] : 0.f;
                    sQ[SWZ64(i, jcol)] = f2b(q);
                }
            }
        }
        #pragma unroll
        for (int kk = 0; kk < 2; ++kk) {
            const int kc = kk * 32 + l4 * 8;
            bf16x8 qa0 = *reinterpret_cast<const bf16x8*>(&sQ[SWZ64(w32 + l15, kc)]);
            bf16x8 qa1 = *reinterpret_cast<const bf16x8*>(&sQ[SWZ64(w32 + 16 + l15, kc)]);
            #pragma unroll
            for (int np = 0; np < 4; ++np) {
                bf16x8 xf = *reinterpret_cast<const bf16x8*>(&sXT[SWZ128(np * 16 + l15, j0 + kc)]);
                yac[0][np] = __builtin_amdgcn_mfma_f32_16x16x32_bf16(qa0, xf, yac[0][np], 0, 0, 0);
                yac[1][np] = __builtin_amdgcn_mfma_f32_16x16x32_bf16(qa1, xf, yac[1][np], 0, 0, 0);
            }
        }
    }
    #pragma unroll
    for (int kk = 0; kk < 2; ++kk) {
        const int kc = kk * 32 + l4 * 8;
        bf16x8 cf0 = *reinterpret_cast<const bf16x8*>(&sC[SWZ64(w32 + l15, kc)]);
        bf16x8 cf1 = *reinterpret_cast<const bf16x8*>(&sC[SWZ64(w32 + 16 + l15, kc)]);
        #pragma unroll
        for (int np = 0; np < 4; ++np) {
            bf16x8 pf = *reinterpret_cast<const bf16x8*>(&sP[SWZ64(np * 16 + l15, kc)]);
            iac[0][np] = __builtin_amdgcn_mfma_f32_16x16x32_bf16(cf0, pf, iac[0][np], 0, 0, 0);
            iac[1][np] = __builtin_amdgcn_mfma_f32_16x16x32_bf16(cf1, pf, iac[1][np], 0, 0, 0);
        }
    }
    const float dh = Dvec[h];
    #pragma unroll
    for (int mi = 0; mi < 2; ++mi) {
        #pragma unroll
        for (int jj = 0; jj < 4; ++jj) {
            const int i = w32 + mi * 16 + l4 * 4 + jj;
            const float ei = __expf(cum[i]);
            const long m = mbase + i;
            const bf16_t* zr = xb + m * (long)IN_OUT + CONV_DIM + h * 64;
            bf16_t* orow = yz + m * (long)D_INNER + h * 64;
            #pragma unroll
            for (int np = 0; np < 4; ++np) {
                const int p = np * 16 + l15;
                const float xval = b2f(sXT[SWZ128(p, i)]);
                const float y = yac[mi][np][jj] + ei * iac[mi][np][jj] + dh * xval;
                const float zv = b2f(zr[p]) + zbias[h * 64 + p];
                const float s = zv / (1.f + __expf(-zv));
                orow[p] = f2b(y * s);
            }
        }
    }
}

// ---------------------------------------------------------------------------
extern "C" void kernel_launch(void* const* d_in, const int* in_sizes, int n_in,
                              void* d_out, int out_size, void* d_ws, size_t ws_size,
                              hipStream_t stream)
{
    const float* u      = (const float*)d_in[0];
    const float* W_in   = (const float*)d_in[1];
    const float* conv_w = (const float*)d_in[2];
    const float* conv_b = (const float*)d_in[3];
    const float* Dv     = (const float*)d_in[4];
    const float* z_bias = (const float*)d_in[5];
    const float* W_out  = (const float*)d_in[6];
    float* out = (float*)d_out;

    char* w = (char*)d_ws;
    bf16_t* xbcza = (bf16_t*)w;  w += (long)M_ROWS * IN_OUT * 2;   // 128.5 MiB
    bf16_t* wob   = (bf16_t*)w;  w += (long)2048 * 2048 * 2;       //   8 MiB
    char* ureg = w;                                                 // ~66 MiB union
    bf16_t* ub  = (bf16_t*)ureg;                                    // 32 MiB (phase 1)
    bf16_t* wib = (bf16_t*)(ureg + (long)M_ROWS * D_MODEL * 2);     // 32.125 MiB (phase 1)
    bf16_t* yzb = (bf16_t*)ureg;                                    // 32 MiB (phase 2)
    float*  cumb   = (float*)(ureg + (long)M_ROWS * D_INNER * 2);   //  1 MiB
    bf16_t* states = (bf16_t*)(cumb + (long)BATCH * NCHUNK * N_QK * CHUNK); // 16 MiB
    float*  cdec   = (float*)(states + (long)BATCH * NCHUNK * N_QK * 4096); //  8 KiB

    f2b_kernel<<<(int)(((long)M_ROWS * D_MODEL / 4 + 255) / 256), 256, 0, stream>>>(
        u, ub, (long)M_ROWS * D_MODEL);
    f2b_kernel<<<(int)(((long)IN_OUT * D_MODEL / 4 + 255) / 256), 256, 0, stream>>>(
        W_in, wib, (long)IN_OUT * D_MODEL);
    f2b_kernel<<<(int)(((long)D_MODEL * D_INNER / 4 + 255) / 256), 256, 0, stream>>>(
        W_out, wob, (long)D_MODEL * D_INNER);

    // GEMM1 main: cols [0, 8192), 1024 wgs, bn-major for per-XCD B residency
    gemm256<32, D_MODEL, true, true><<<(M_ROWS / 256) * 32, 512, 0, stream>>>(
        ub, wib, xbcza, IN_OUT);
    // GEMM1 tail: cols [8192, 8224) (A_log)
    gemm_mfma<32, D_MODEL, true><<<(M_ROWS / 128), 256, 0, stream>>>(
        ub, wib + (long)8192 * D_MODEL, xbcza + 8192, IN_OUT);

    ssd_states<<<dim3(N_QK, NCHUNK, BATCH), 256, 0, stream>>>(xbcza, conv_w, conv_b,
                                                              states, cumb, cdec);

    ssd_scan<<<BATCH * N_QK * 4, 256, 0, stream>>>(states, cdec);

    ssd_out<<<dim3(N_QK, NCHUNK, BATCH), 256, 0, stream>>>(xbcza, cumb, states, Dv, z_bias,
                                                           conv_w, conv_b, yzb);

    // GEMM2: out = yz @ W_out^T  (8192 x 2048 x 2048), 256 wgs, bm-major
    gemm256<8, D_INNER, false, false><<<(M_ROWS / 256) * 8, 512, 0, stream>>>(
        yzb, wob, out, D_MODEL);
}

// Round 11
// 824.388 us; speedup vs baseline: 1.0183x; 1.0183x over previous
//
#include <hip/hip_runtime.h>
#include <math.h>

#define D_MODEL  2048
#define D_INNER  2048
#define N_QK     32
#define N_V      32
#define D_STATE  64
#define D_CONV   4
#define CHUNK    128
#define CONV_DIM 6144      // D_INNER + 2*N_QK*D_STATE
#define IN_OUT   8224      // 2*D_INNER + 2*N_QK*D_STATE + N_V
#define BATCH    2
#define SEQ      4096
#define M_ROWS   (BATCH*SEQ)   // 8192
#define NCHUNK   (SEQ/CHUNK)   // 32

typedef unsigned short bf16_t;
typedef __attribute__((ext_vector_type(4))) float f32x4;
typedef __attribute__((ext_vector_type(8))) short bf16x8;

// swizzled row-major LDS index (elem units); XOR bits 3-5 spread rows over banks
#define SWZ64(r,c)  ((((r)*64)  + (c)) ^ (((r)&7)<<3))
#define SWZ128(r,c) ((((r)*128) + (c)) ^ (((r)&7)<<3))

__device__ __forceinline__ float b2f(bf16_t u) {
    union { unsigned int i; float f; } w; w.i = ((unsigned int)u) << 16; return w.f;
}
__device__ __forceinline__ bf16_t f2b(float f) {
    unsigned int x = __float_as_uint(f);
    return (bf16_t)((x + 0x7FFFu + ((x >> 16) & 1u)) >> 16);   // RNE
}
__device__ __forceinline__ void store4b(bf16_t* dst, float4 v) {
    ushort4 u; u.x = f2b(v.x); u.y = f2b(v.y); u.z = f2b(v.z); u.w = f2b(v.w);
    *reinterpret_cast<ushort4*>(dst) = u;
}

__device__ __forceinline__ void gload_lds16(const bf16_t* g, bf16_t* l) {
    __builtin_amdgcn_global_load_lds((const __attribute__((address_space(1))) void*)g,
                                     (__attribute__((address_space(3))) void*)l,
                                     16, 0, 0);
}

// ---------------------------------------------------------------------------
// fused fp32 -> bf16 convert for 3 segments (u, W_in, W_out) in one dispatch
// ---------------------------------------------------------------------------
__global__ __launch_bounds__(256) void f2b3_kernel(const float* __restrict__ a0, bf16_t* __restrict__ o0, long n0,
                                                   const float* __restrict__ a1, bf16_t* __restrict__ o1, long n1,
                                                   const float* __restrict__ a2, bf16_t* __restrict__ o2, long n2)
{
    long i = ((long)blockIdx.x * 256 + threadIdx.x) * 4;
    const float* in; bf16_t* out;
    if (i < n0)            { in = a0 + i; out = o0 + i; }
    else if (i < n0 + n1)  { i -= n0; in = a1 + i; out = o1 + i; }
    else if (i < n0 + n1 + n2) { i -= n0 + n1; in = a2 + i; out = o2 + i; }
    else return;
    float4 v = *reinterpret_cast<const float4*>(in);
    ushort4 o;
    o.x = f2b(v.x); o.y = f2b(v.y); o.z = f2b(v.z); o.w = f2b(v.w);
    *reinterpret_cast<ushort4*>(out) = o;
}

// ---------------------------------------------------------------------------
// 256x256 bf16 MFMA NT-GEMM, K-half counted-vmcnt pipeline (R9-proven, bm-major).
// ---------------------------------------------------------------------------
template<int NTB, int K, bool OBF16>
__global__ __launch_bounds__(512, 2) void gemm256(const bf16_t* __restrict__ A,
                                                  const bf16_t* __restrict__ B,
                                                  void* __restrict__ Cv,
                                                  long ldc)
{
    constexpr int BK = 64;
    constexpr int NT = K / BK;
    __shared__ bf16_t As[2][2][8192];   // [buf][kh][1024 slots * 8 elems]
    __shared__ bf16_t Bs[2][2][8192];

    const int nwg = gridDim.x;
    const int bid = blockIdx.x;
    const int wg  = ((nwg & 7) == 0) ? ((bid & 7) * (nwg >> 3) + (bid >> 3)) : bid;
    const int bm = (wg / NTB) * 256;
    const int bn = (wg % NTB) * 256;

    const int tid  = threadIdx.x;
    const int lane = tid & 63;
    const int wv   = tid >> 6;
    const int wr   = wv >> 2, wc = wv & 3;       // 2x4 wave grid
    const int l15  = lane & 15, l4 = lane >> 4;

    f32x4 acc[8][4];
    #pragma unroll
    for (int i = 0; i < 8; ++i)
        #pragma unroll
        for (int j = 0; j < 4; ++j) acc[i][j] = (f32x4){0.f, 0.f, 0.f, 0.f};

    const bf16_t* Abase = A + (long)bm * K;
    const bf16_t* Bbase = B + (long)bn * K;

    auto stage_half = [&](int t, int buf, int kh) {
        #pragma unroll
        for (int it = 0; it < 2; ++it) {
            const int s   = it * 512 + tid;          // 0..1023
            const int row = s >> 2;                  // 0..255
            const int jp  = s & 3;                   // physical chunk in half
            const int jl  = jp ^ ((row >> 1) & 3);   // logical chunk in half
            const long go = (long)row * K + t * BK + kh * 32 + jl * 8;
            gload_lds16(Abase + go, &As[buf][kh][s * 8]);
            gload_lds16(Bbase + go, &Bs[buf][kh][s * 8]);
        }
    };
    auto rdA = [&](int buf, int kh, int row) {
        const int jp = l4 ^ ((row >> 1) & 3);
        return *reinterpret_cast<const bf16x8*>(&As[buf][kh][(row * 4 + jp) * 8]);
    };
    auto rdB = [&](int buf, int kh, int row) {
        const int jp = l4 ^ ((row >> 1) & 3);
        return *reinterpret_cast<const bf16x8*>(&Bs[buf][kh][(row * 4 + jp) * 8]);
    };

    stage_half(0, 0, 0);
    stage_half(0, 0, 1);
    asm volatile("s_waitcnt vmcnt(4)" ::: "memory");   // K-half0 of tile 0 landed
    __builtin_amdgcn_s_barrier();

    for (int t = 0; t < NT; ++t) {
        const int cur = t & 1;
        bf16x8 bfr[4], af[4];
        if (t + 1 < NT) stage_half(t + 1, cur ^ 1, 0);
        // P1: ks=0, qm=0
        #pragma unroll
        for (int ni = 0; ni < 4; ++ni) bfr[ni] = rdB(cur, 0, wc * 64 + ni * 16 + l15);
        #pragma unroll
        for (int mi = 0; mi < 4; ++mi) af[mi] = rdA(cur, 0, wr * 128 + mi * 16 + l15);
        __builtin_amdgcn_s_setprio(1);
        #pragma unroll
        for (int mi = 0; mi < 4; ++mi)
            #pragma unroll
            for (int ni = 0; ni < 4; ++ni)
                acc[mi][ni] = __builtin_amdgcn_mfma_f32_16x16x32_bf16(
                    af[mi], bfr[ni], acc[mi][ni], 0, 0, 0);
        __builtin_amdgcn_s_setprio(0);
        __builtin_amdgcn_s_barrier();
        // P2: ks=0, qm=1
        #pragma unroll
        for (int mi = 0; mi < 4; ++mi) af[mi] = rdA(cur, 0, wr * 128 + 64 + mi * 16 + l15);
        __builtin_amdgcn_s_setprio(1);
        #pragma unroll
        for (int mi = 0; mi < 4; ++mi)
            #pragma unroll
            for (int ni = 0; ni < 4; ++ni)
                acc[4 + mi][ni] = __builtin_amdgcn_mfma_f32_16x16x32_bf16(
                    af[mi], bfr[ni], acc[4 + mi][ni], 0, 0, 0);
        __builtin_amdgcn_s_setprio(0);
        if (t + 1 < NT) {
            stage_half(t + 1, cur ^ 1, 1);
            asm volatile("s_waitcnt vmcnt(8)" ::: "memory");   // K1(t) landed
        } else {
            asm volatile("s_waitcnt vmcnt(0)" ::: "memory");
        }
        __builtin_amdgcn_s_barrier();
        // P3: ks=1, qm=0
        #pragma unroll
        for (int ni = 0; ni < 4; ++ni) bfr[ni] = rdB(cur, 1, wc * 64 + ni * 16 + l15);
        #pragma unroll
        for (int mi = 0; mi < 4; ++mi) af[mi] = rdA(cur, 1, wr * 128 + mi * 16 + l15);
        __builtin_amdgcn_s_setprio(1);
        #pragma unroll
        for (int mi = 0; mi < 4; ++mi)
            #pragma unroll
            for (int ni = 0; ni < 4; ++ni)
                acc[mi][ni] = __builtin_amdgcn_mfma_f32_16x16x32_bf16(
                    af[mi], bfr[ni], acc[mi][ni], 0, 0, 0);
        __builtin_amdgcn_s_setprio(0);
        __builtin_amdgcn_s_barrier();
        // P4: ks=1, qm=1
        #pragma unroll
        for (int mi = 0; mi < 4; ++mi) af[mi] = rdA(cur, 1, wr * 128 + 64 + mi * 16 + l15);
        __builtin_amdgcn_s_setprio(1);
        #pragma unroll
        for (int mi = 0; mi < 4; ++mi)
            #pragma unroll
            for (int ni = 0; ni < 4; ++ni)
                acc[4 + mi][ni] = __builtin_amdgcn_mfma_f32_16x16x32_bf16(
                    af[mi], bfr[ni], acc[4 + mi][ni], 0, 0, 0);
        __builtin_amdgcn_s_setprio(0);
        if (t + 1 < NT) { asm volatile("s_waitcnt vmcnt(4)" ::: "memory"); }
        __builtin_amdgcn_s_barrier();
    }

    #pragma unroll
    for (int mf = 0; mf < 8; ++mf) {
        const long grow0 = bm + wr * 128 + mf * 16 + l4 * 4;
        #pragma unroll
        for (int ni = 0; ni < 4; ++ni) {
            const int gcol = bn + wc * 64 + ni * 16 + l15;
            #pragma unroll
            for (int j = 0; j < 4; ++j) {
                if (OBF16)
                    ((bf16_t*)Cv)[(grow0 + j) * ldc + gcol] = f2b(acc[mf][ni][j]);
                else
                    ((float*)Cv)[(grow0 + j) * ldc + gcol] = acc[mf][ni][j];
            }
        }
    }
}

// ---------------------------------------------------------------------------
// 128x128 m97-style MFMA GEMM (A_log 32-col tail), ldc-param.
// ---------------------------------------------------------------------------
template<int N, int K, bool OBF16>
__global__ __launch_bounds__(256) void gemm_mfma(const bf16_t* __restrict__ A,
                                                 const bf16_t* __restrict__ B,
                                                 void* __restrict__ Cv,
                                                 long ldc)
{
    constexpr int BM = 128, BN = 128, BK = 64;
    constexpr int NTB = (N + BN - 1) / BN;
    __shared__ bf16_t As[BM * BK];
    __shared__ bf16_t Bs[BM * BK];

    const int nwg = gridDim.x;
    const int bid = blockIdx.x;
    const int wg  = ((nwg & 7) == 0) ? ((bid & 7) * (nwg >> 3) + (bid >> 3)) : bid;
    const int bm = (wg / NTB) * BM;
    const int bn = (wg % NTB) * BN;

    const int tid  = threadIdx.x;
    const int lane = tid & 63;
    const int wv   = tid >> 6;
    const int wr   = wv >> 1, wc = wv & 1;

    f32x4 acc[4][4];
    #pragma unroll
    for (int i = 0; i < 4; ++i)
        #pragma unroll
        for (int j = 0; j < 4; ++j) acc[i][j] = (f32x4){0.f, 0.f, 0.f, 0.f};

    for (int k0 = 0; k0 < K; k0 += BK) {
        #pragma unroll
        for (int it = 0; it < 4; ++it) {
            const int seg = it * 256 + tid;
            const int row = seg >> 3, c16 = seg & 7;
            gload_lds16(A + (long)(bm + row) * K + k0 + c16 * 8,
                        &As[row * BK + c16 * 8]);
            int brow = bn + row;
            if constexpr (N % BN != 0) brow = min(brow, N - 1);
            gload_lds16(B + (long)brow * K + k0 + c16 * 8,
                        &Bs[row * BK + c16 * 8]);
        }
        __syncthreads();
        #pragma unroll
        for (int kk = 0; kk < 2; ++kk) {
            bf16x8 af[4], bfr[4];
            const int kc = kk * 32 + (lane >> 4) * 8;
            #pragma unroll
            for (int mi = 0; mi < 4; ++mi) {
                const int row = wr * 64 + mi * 16 + (lane & 15);
                af[mi] = *reinterpret_cast<const bf16x8*>(&As[row * BK + kc]);
            }
            #pragma unroll
            for (int ni = 0; ni < 4; ++ni) {
                const int row = wc * 64 + ni * 16 + (lane & 15);
                bfr[ni] = *reinterpret_cast<const bf16x8*>(&Bs[row * BK + kc]);
            }
            #pragma unroll
            for (int mi = 0; mi < 4; ++mi)
                #pragma unroll
                for (int ni = 0; ni < 4; ++ni)
                    acc[mi][ni] = __builtin_amdgcn_mfma_f32_16x16x32_bf16(
                        af[mi], bfr[ni], acc[mi][ni], 0, 0, 0);
        }
        __syncthreads();
    }

    #pragma unroll
    for (int mi = 0; mi < 4; ++mi) {
        const long row0 = bm + wr * 64 + mi * 16 + ((lane >> 4) << 2);
        #pragma unroll
        for (int ni = 0; ni < 4; ++ni) {
            const int col = bn + wc * 64 + ni * 16 + (lane & 15);
            if (N % BN != 0 && col >= N) continue;
            #pragma unroll
            for (int j = 0; j < 4; ++j) {
                if (OBF16)
                    ((bf16_t*)Cv)[(row0 + j) * ldc + col] = f2b(acc[mi][ni][j]);
                else
                    ((float*)Cv)[(row0 + j) * ldc + col] = acc[mi][ni][j];
            }
        }
    }
}

// ---------------------------------------------------------------------------
// Fused causal depthwise conv (K=4), 4 consecutive columns, reading bf16 xBCzA.
// ---------------------------------------------------------------------------
__device__ __forceinline__ float4 conv4v(const bf16_t* __restrict__ xb, long m, int l,
                                         int col, const float* __restrict__ cw,
                                         const float* __restrict__ cbv)
{
    float4 acc = *reinterpret_cast<const float4*>(cbv + col);
    float4 wc0 = *reinterpret_cast<const float4*>(cw + (long)col * 4);
    float4 wc1 = *reinterpret_cast<const float4*>(cw + (long)col * 4 + 4);
    float4 wc2 = *reinterpret_cast<const float4*>(cw + (long)col * 4 + 8);
    float4 wc3 = *reinterpret_cast<const float4*>(cw + (long)col * 4 + 12);
    const float t0[4] = {wc0.x, wc0.y, wc0.z, wc0.w};
    const float t1[4] = {wc1.x, wc1.y, wc1.z, wc1.w};
    const float t2[4] = {wc2.x, wc2.y, wc2.z, wc2.w};
    const float t3[4] = {wc3.x, wc3.y, wc3.z, wc3.w};
    #pragma unroll
    for (int tap = 0; tap < 4; ++tap) {
        if (l - 3 + tap < 0) continue;
        const bf16_t* p = xb + (m - 3 + tap) * (long)IN_OUT + col;
        ushort4 v = *reinterpret_cast<const ushort4*>(p);
        acc.x = fmaf(b2f(v.x), t0[tap], acc.x);
        acc.y = fmaf(b2f(v.y), t1[tap], acc.y);
        acc.z = fmaf(b2f(v.z), t2[tap], acc.z);
        acc.w = fmaf(b2f(v.w), t3[tap], acc.w);
    }
    return acc;
}

// ---------------------------------------------------------------------------
// Phase A (MFMA): dt=softplus (self), wave-shuffle cumsum, states via MFMA.
// EXP: additionally export conv'd B (SWZ64-phys) and x^T (SWZ128-phys) to
// global so ssd_out can stage them with direct global_load_lds (no re-conv).
// ---------------------------------------------------------------------------
template<bool EXP>
__global__ __launch_bounds__(256) void ssd_states(const bf16_t* __restrict__ xb,
                                                  const float* __restrict__ cw,
                                                  const float* __restrict__ cbv,
                                                  bf16_t* __restrict__ states,
                                                  float* __restrict__ cumbuf,
                                                  float* __restrict__ cdecay,
                                                  bf16_t* __restrict__ xtg,
                                                  bf16_t* __restrict__ bg)
{
    const int h = blockIdx.x, c = blockIdx.y, b = blockIdx.z;
    __shared__ bf16_t sx [128 * 64];
    __shared__ bf16_t sBr[128 * 64];
    __shared__ bf16_t sXT[64 * 128];
    __shared__ bf16_t sBT[64 * 128];
    __shared__ float  cum[CHUNK];
    __shared__ float  w0tot;
    const int t = threadIdx.x;
    const long mbase = (long)b * SEQ + (long)c * CHUNK;
    const long cb = ((long)b * NCHUNK + c) * N_QK + h;

    // softplus + wave-level inclusive scan (6 shfl steps, no barriers)
    float v = 0.f;
    if (t < CHUNK) {
        const float a = b2f(xb[(mbase + t) * (long)IN_OUT + (CONV_DIM + D_INNER) + h]);
        v = -((a > 20.f) ? a : log1pf(expf(a)));
        #pragma unroll
        for (int s = 1; s < 64; s <<= 1) {
            const float u2 = __shfl_up(v, s, 64);
            if ((t & 63) >= s) v += u2;
        }
        if (t == 63) w0tot = v;
    }
    for (int idx = t; idx < CHUNK * 16; idx += 256) {
        const int k = idx >> 4, q4 = (idx & 15) * 4;
        const long m = mbase + k;
        const int l = (int)(m & (SEQ - 1));
        float4 xv = conv4v(xb, m, l, h * 64 + q4, cw, cbv);
        float4 bv = conv4v(xb, m, l, D_INNER + h * 64 + q4, cw, cbv);
        store4b(&sx [SWZ64(k, q4)], xv);
        store4b(&sBr[SWZ64(k, q4)], bv);
    }
    __syncthreads();
    if (t >= 64 && t < CHUNK) v += w0tot;
    if (t < CHUNK) cum[t] = v;
    __syncthreads();
    const float clast = cum[CHUNK - 1];
    // transpose x -> sXT; B*decay -> sBT
    {
        const int j = t & 127;
        const int c8b = (t >> 7) * 4;
        const float ej = __expf(clast - cum[j]);
        #pragma unroll
        for (int it = 0; it < 4; ++it) {
            const int c8 = c8b + it;
            bf16x8 xv = *reinterpret_cast<const bf16x8*>(&sx [SWZ64(j, c8 * 8)]);
            bf16x8 bv = *reinterpret_cast<const bf16x8*>(&sBr[SWZ64(j, c8 * 8)]);
            #pragma unroll
            for (int e = 0; e < 8; ++e) {
                sXT[SWZ128(c8 * 8 + e, j)] = xv[e];
                sBT[SWZ128(c8 * 8 + e, j)] = f2b(b2f((bf16_t)bv[e]) * ej);
            }
        }
    }
    __syncthreads();

    const int lane = t & 63, wv = t >> 6;
    const int l15 = lane & 15, l4 = lane >> 4;
    f32x4 acc[4];
    #pragma unroll
    for (int nj = 0; nj < 4; ++nj) acc[nj] = (f32x4){0.f, 0.f, 0.f, 0.f};
    #pragma unroll
    for (int ks = 0; ks < 4; ++ks) {
        const int kc = ks * 32 + l4 * 8;
        bf16x8 af = *reinterpret_cast<const bf16x8*>(&sXT[SWZ128(wv * 16 + l15, kc)]);
        #pragma unroll
        for (int nj = 0; nj < 4; ++nj) {
            bf16x8 bf = *reinterpret_cast<const bf16x8*>(&sBT[SWZ128(nj * 16 + l15, kc)]);
            acc[nj] = __builtin_amdgcn_mfma_f32_16x16x32_bf16(af, bf, acc[nj], 0, 0, 0);
        }
    }
    // write bf16, SWZ64-physical within the 4096-elem block
    #pragma unroll
    for (int nj = 0; nj < 4; ++nj) {
        #pragma unroll
        for (int jj = 0; jj < 4; ++jj) {
            const int p = wv * 16 + l4 * 4 + jj;
            states[cb * 4096 + SWZ64(p, nj * 16 + l15)] = f2b(acc[nj][jj]);
        }
    }
    if constexpr (EXP) {
        // export x^T (SWZ128-phys) and B (SWZ64-phys) as linear 16B copies;
        // sXT/sBr unchanged since the pre-MFMA barrier.
        #pragma unroll
        for (int it = 0; it < 4; ++it) {
            const int s = it * 256 + t;   // 1024 slots of 8 elems
            *reinterpret_cast<bf16x8*>(xtg + cb * 8192 + s * 8) =
                *reinterpret_cast<const bf16x8*>(&sXT[s * 8]);
            *reinterpret_cast<bf16x8*>(bg + cb * 8192 + s * 8) =
                *reinterpret_cast<const bf16x8*>(&sBr[s * 8]);
        }
    }
    if (t < CHUNK) cumbuf[cb * CHUNK + t] = cum[t];
    if (t == 0)   cdecay[cb] = __expf(clast);
}

// ---------------------------------------------------------------------------
// Phase B: sequential inter-chunk scan over bf16 states (carry in f32).
// ---------------------------------------------------------------------------
__global__ __launch_bounds__(256) void ssd_scan(bf16_t* __restrict__ states,
                                                const float* __restrict__ cdecay)
{
    const int bid = blockIdx.x;
    const int bh = bid >> 2, q = bid & 3;
    const int b = bh >> 5, h = bh & 31;
    const int t = threadIdx.x;
    const int off = q * 1024 + t * 4;
    float4 carry = make_float4(0.f, 0.f, 0.f, 0.f);
    for (int c = 0; c < NCHUNK; ++c) {
        const long cb = ((long)b * NCHUNK + c) * N_QK + h;
        bf16_t* p = states + cb * 4096 + off;
        const float cd = cdecay[cb];
        ushort4 su = *reinterpret_cast<const ushort4*>(p);
        ushort4 pv;
        pv.x = f2b(carry.x); pv.y = f2b(carry.y);
        pv.z = f2b(carry.z); pv.w = f2b(carry.w);
        *reinterpret_cast<ushort4*>(p) = pv;
        carry.x = fmaf(carry.x, cd, b2f(su.x));
        carry.y = fmaf(carry.y, cd, b2f(su.y));
        carry.z = fmaf(carry.z, cd, b2f(su.z));
        carry.w = fmaf(carry.w, cd, b2f(su.w));
    }
}

// ---------------------------------------------------------------------------
// Phase C (MFMA): S=C·B^T (tri+decay) -> Q bf16 -> y = Q·x + e·(C·prev^T) + D·x
// gate silu(z+zb) -> yz bf16. EXP: x^T and B staged by direct global_load_lds
// from ssd_states' exports (conv already applied); only C needs conv.
// ---------------------------------------------------------------------------
template<bool EXP>
__global__ __launch_bounds__(256) void ssd_out(const bf16_t* __restrict__ xb,
                                               const float* __restrict__ cumbuf,
                                               const bf16_t* __restrict__ prevst,
                                               const float* __restrict__ Dvec,
                                               const float* __restrict__ zbias,
                                               const float* __restrict__ cw,
                                               const float* __restrict__ cbv,
                                               const bf16_t* __restrict__ xtg,
                                               const bf16_t* __restrict__ bg,
                                               bf16_t* __restrict__ yz)
{
    const int h = blockIdx.x, c = blockIdx.y, b = blockIdx.z;
    __shared__ bf16_t sC[128 * 64];
    __shared__ bf16_t sB[128 * 64];
    __shared__ bf16_t sXQ[128 * 64];   // x tile (FB) / Q scratch
    __shared__ bf16_t sXT[64 * 128];   // x^T
    __shared__ bf16_t sP[64 * 64];     // prev state (bf16, SWZ64-physical)
    __shared__ float  cum[CHUNK];
    const int t = threadIdx.x;
    const long mbase = (long)b * SEQ + (long)c * CHUNK;
    const long cb = ((long)b * NCHUNK + c) * N_QK + h;
    if (t < CHUNK) cum[t] = cumbuf[cb * CHUNK + t];
    // prev: direct linear copy (global already SWZ64-physical)
    #pragma unroll
    for (int it = 0; it < 2; ++it) {
        const int s = it * 256 + t;             // 512 slots of 16B
        gload_lds16(prevst + cb * 4096 + s * 8, &sP[s * 8]);
    }
    if constexpr (EXP) {
        #pragma unroll
        for (int it = 0; it < 4; ++it) {
            const int s = it * 256 + t;         // 1024 slots of 16B each
            gload_lds16(bg  + cb * 8192 + s * 8, &sB [s * 8]);
            gload_lds16(xtg + cb * 8192 + s * 8, &sXT[s * 8]);
        }
        for (int idx = t; idx < CHUNK * 16; idx += 256) {
            const int k = idx >> 4, q4 = (idx & 15) * 4;
            const long m = mbase + k;
            const int l = (int)(m & (SEQ - 1));
            float4 cv = conv4v(xb, m, l, 2 * D_INNER + h * 64 + q4, cw, cbv);
            store4b(&sC[SWZ64(k, q4)], cv);
        }
        __syncthreads();   // drains vmcnt+lgkmcnt (compiler-inserted)
    } else {
        for (int idx = t; idx < CHUNK * 16; idx += 256) {
            const int k = idx >> 4, q4 = (idx & 15) * 4;
            const long m = mbase + k;
            const int l = (int)(m & (SEQ - 1));
            float4 xv = conv4v(xb, m, l, h * 64 + q4, cw, cbv);
            float4 bv = conv4v(xb, m, l, D_INNER + h * 64 + q4, cw, cbv);
            float4 cv = conv4v(xb, m, l, 2 * D_INNER + h * 64 + q4, cw, cbv);
            store4b(&sXQ[SWZ64(k, q4)], xv);
            store4b(&sB [SWZ64(k, q4)], bv);
            store4b(&sC [SWZ64(k, q4)], cv);
        }
        __syncthreads();
        {
            const int j = t & 127;
            const int c8b = (t >> 7) * 4;
            #pragma unroll
            for (int it = 0; it < 4; ++it) {
                const int c8 = c8b + it;
                bf16x8 v = *reinterpret_cast<const bf16x8*>(&sXQ[SWZ64(j, c8 * 8)]);
                #pragma unroll
                for (int e = 0; e < 8; ++e) sXT[SWZ128(c8 * 8 + e, j)] = v[e];
            }
        }
        __syncthreads();   // sXQ now dead as x; becomes wave-private Q
    }

    const int lane = t & 63, wv = t >> 6;
    const int w32 = wv * 32, l15 = lane & 15, l4 = lane >> 4;
    bf16_t* sQ = sXQ;

    f32x4 yac[2][4], iac[2][4];
    #pragma unroll
    for (int mi = 0; mi < 2; ++mi)
        #pragma unroll
        for (int np = 0; np < 4; ++np) {
            yac[mi][np] = (f32x4){0.f, 0.f, 0.f, 0.f};
            iac[mi][np] = (f32x4){0.f, 0.f, 0.f, 0.f};
        }

    #pragma unroll
    for (int H = 0; H < 2; ++H) {
        if (H == 1 && wv < 2) break;
        const int j0 = H * 64;
        f32x4 sac[2][4];
        #pragma unroll
        for (int mi = 0; mi < 2; ++mi)
            #pragma unroll
            for (int nj = 0; nj < 4; ++nj) sac[mi][nj] = (f32x4){0.f, 0.f, 0.f, 0.f};
        #pragma unroll
        for (int kk = 0; kk < 2; ++kk) {
            const int kc = kk * 32 + l4 * 8;
            bf16x8 af0 = *reinterpret_cast<const bf16x8*>(&sC[SWZ64(w32 + l15, kc)]);
            bf16x8 af1 = *reinterpret_cast<const bf16x8*>(&sC[SWZ64(w32 + 16 + l15, kc)]);
            #pragma unroll
            for (int nj = 0; nj < 4; ++nj) {
                bf16x8 bfj = *reinterpret_cast<const bf16x8*>(&sB[SWZ64(j0 + nj * 16 + l15, kc)]);
                if (j0 + nj * 16 <= w32 + 15)
                    sac[0][nj] = __builtin_amdgcn_mfma_f32_16x16x32_bf16(af0, bfj, sac[0][nj], 0, 0, 0);
                if (j0 + nj * 16 <= w32 + 31)
                    sac[1][nj] = __builtin_amdgcn_mfma_f32_16x16x32_bf16(af1, bfj, sac[1][nj], 0, 0, 0);
            }
        }
        #pragma unroll
        for (int mi = 0; mi < 2; ++mi) {
            #pragma unroll
            for (int nj = 0; nj < 4; ++nj) {
                const int jcol = nj * 16 + l15;
                const int jg = j0 + jcol;
                #pragma unroll
                for (int jj = 0; jj < 4; ++jj) {
                    const int i = w32 + mi * 16 + l4 * 4 + jj;
                    const float q = (jg <= i) ? __expf(cum[i] - cum[jg]) * sac[mi][nj][jj] : 0.f;
                    sQ[SWZ64(i, jcol)] = f2b(q);
                }
            }
        }
        #pragma unroll
        for (int kk = 0; kk < 2; ++kk) {
            const int kc = kk * 32 + l4 * 8;
            bf16x8 qa0 = *reinterpret_cast<const bf16x8*>(&sQ[SWZ64(w32 + l15, kc)]);
            bf16x8 qa1 = *reinterpret_cast<const bf16x8*>(&sQ[SWZ64(w32 + 16 + l15, kc)]);
            #pragma unroll
            for (int np = 0; np < 4; ++np) {
                bf16x8 xf = *reinterpret_cast<const bf16x8*>(&sXT[SWZ128(np * 16 + l15, j0 + kc)]);
                yac[0][np] = __builtin_amdgcn_mfma_f32_16x16x32_bf16(qa0, xf, yac[0][np], 0, 0, 0);
                yac[1][np] = __builtin_amdgcn_mfma_f32_16x16x32_bf16(qa1, xf, yac[1][np], 0, 0, 0);
            }
        }
    }
    #pragma unroll
    for (int kk = 0; kk < 2; ++kk) {
        const int kc = kk * 32 + l4 * 8;
        bf16x8 cf0 = *reinterpret_cast<const bf16x8*>(&sC[SWZ64(w32 + l15, kc)]);
        bf16x8 cf1 = *reinterpret_cast<const bf16x8*>(&sC[SWZ64(w32 + 16 + l15, kc)]);
        #pragma unroll
        for (int np = 0; np < 4; ++np) {
            bf16x8 pf = *reinterpret_cast<const bf16x8*>(&sP[SWZ64(np * 16 + l15, kc)]);
            iac[0][np] = __builtin_amdgcn_mfma_f32_16x16x32_bf16(cf0, pf, iac[0][np], 0, 0, 0);
            iac[1][np] = __builtin_amdgcn_mfma_f32_16x16x32_bf16(cf1, pf, iac[1][np], 0, 0, 0);
        }
    }
    const float dh = Dvec[h];
    #pragma unroll
    for (int mi = 0; mi < 2; ++mi) {
        #pragma unroll
        for (int jj = 0; jj < 4; ++jj) {
            const int i = w32 + mi * 16 + l4 * 4 + jj;
            const float ei = __expf(cum[i]);
            const long m = mbase + i;
            const bf16_t* zr = xb + m * (long)IN_OUT + CONV_DIM + h * 64;
            bf16_t* orow = yz + m * (long)D_INNER + h * 64;
            #pragma unroll
            for (int np = 0; np < 4; ++np) {
                const int p = np * 16 + l15;
                const float xval = b2f(sXT[SWZ128(p, i)]);
                const float y = yac[mi][np][jj] + ei * iac[mi][np][jj] + dh * xval;
                const float zv = b2f(zr[p]) + zbias[h * 64 + p];
                const float s = zv / (1.f + __expf(-zv));
                orow[p] = f2b(y * s);
            }
        }
    }
}

// ---------------------------------------------------------------------------
extern "C" void kernel_launch(void* const* d_in, const int* in_sizes, int n_in,
                              void* d_out, int out_size, void* d_ws, size_t ws_size,
                              hipStream_t stream)
{
    const float* u      = (const float*)d_in[0];
    const float* W_in   = (const float*)d_in[1];
    const float* conv_w = (const float*)d_in[2];
    const float* conv_b = (const float*)d_in[3];
    const float* Dv     = (const float*)d_in[4];
    const float* z_bias = (const float*)d_in[5];
    const float* W_out  = (const float*)d_in[6];
    float* out = (float*)d_out;

    char* w = (char*)d_ws;
    bf16_t* xbcza = (bf16_t*)w;  w += (long)M_ROWS * IN_OUT * 2;   // 128.5 MiB
    bf16_t* wob   = (bf16_t*)w;  w += (long)2048 * 2048 * 2;       //   8 MiB
    char* ureg = w;  w += 67239936;                                 // 64.1 MiB union
    bf16_t* ub  = (bf16_t*)ureg;                                    // 32 MiB (phase 1)
    bf16_t* wib = (bf16_t*)(ureg + (long)M_ROWS * D_MODEL * 2);     // 32.125 MiB (phase 1)
    bf16_t* yzb = (bf16_t*)ureg;                                    // 32 MiB (phase 2)
    float*  cumb   = (float*)(ureg + (long)M_ROWS * D_INNER * 2);   //  1 MiB
    bf16_t* states = (bf16_t*)(cumb + (long)BATCH * NCHUNK * N_QK * CHUNK); // 16 MiB
    float*  cdec   = (float*)(states + (long)BATCH * NCHUNK * N_QK * 4096); //  8 KiB
    // optional conv-export buffers (64 MiB) -- only if workspace allows
    const long base_bytes = (long)(w - (char*)d_ws);
    const long exp_bytes  = 2L * 2048 * 8192 * 2;                   // xtg + bg
    const bool use_exp = ((long)ws_size >= base_bytes + exp_bytes);
    bf16_t* xtg = (bf16_t*)w;
    bf16_t* bg  = xtg + (long)2048 * 8192;

    // fused fp32->bf16 conversions (u, W_in, W_out)
    {
        const long n0 = (long)M_ROWS * D_MODEL;
        const long n1 = (long)IN_OUT * D_MODEL;
        const long n2 = (long)D_MODEL * D_INNER;
        const long nb = ((n0 + n1 + n2) / 4 + 255) / 256;
        f2b3_kernel<<<(int)nb, 256, 0, stream>>>(u, ub, n0, W_in, wib, n1, W_out, wob, n2);
    }

    // GEMM1 main: cols [0, 8192), 1024 wgs, bm-major (R9 config: 325 us)
    gemm256<32, D_MODEL, true><<<(M_ROWS / 256) * 32, 512, 0, stream>>>(
        ub, wib, xbcza, IN_OUT);
    // GEMM1 tail: cols [8192, 8224) (A_log)
    gemm_mfma<32, D_MODEL, true><<<(M_ROWS / 128), 256, 0, stream>>>(
        ub, wib + (long)8192 * D_MODEL, xbcza + 8192, IN_OUT);

    if (use_exp) {
        ssd_states<true><<<dim3(N_QK, NCHUNK, BATCH), 256, 0, stream>>>(
            xbcza, conv_w, conv_b, states, cumb, cdec, xtg, bg);
        ssd_scan<<<BATCH * N_QK * 4, 256, 0, stream>>>(states, cdec);
        ssd_out<true><<<dim3(N_QK, NCHUNK, BATCH), 256, 0, stream>>>(
            xbcza, cumb, states, Dv, z_bias, conv_w, conv_b, xtg, bg, yzb);
    } else {
        ssd_states<false><<<dim3(N_QK, NCHUNK, BATCH), 256, 0, stream>>>(
            xbcza, conv_w, conv_b, states, cumb, cdec, nullptr, nullptr);
        ssd_scan<<<BATCH * N_QK * 4, 256, 0, stream>>>(states, cdec);
        ssd_out<false><<<dim3(N_QK, NCHUNK, BATCH), 256, 0, stream>>>(
            xbcza, cumb, states, Dv, z_bias, conv_w, conv_b, nullptr, nullptr, yzb);
    }

    // GEMM2: out = yz @ W_out^T  (8192 x 2048 x 2048), 256 wgs
    gemm256<8, D_INNER, false><<<(M_ROWS / 256) * 8, 512, 0, stream>>>(
        yzb, wob, out, D_MODEL);
}

// Round 12
// 805.648 us; speedup vs baseline: 1.0419x; 1.0233x over previous
//
#include <hip/hip_runtime.h>
#include <math.h>

#define D_MODEL  2048
#define D_INNER  2048
#define N_QK     32
#define N_V      32
#define D_STATE  64
#define D_CONV   4
#define CHUNK    128
#define CONV_DIM 6144      // D_INNER + 2*N_QK*D_STATE
#define IN_OUT   8224      // 2*D_INNER + 2*N_QK*D_STATE + N_V
#define BATCH    2
#define SEQ      4096
#define M_ROWS   (BATCH*SEQ)   // 8192
#define NCHUNK   (SEQ/CHUNK)   // 32

typedef unsigned short bf16_t;
typedef __attribute__((ext_vector_type(4))) float f32x4;
typedef __attribute__((ext_vector_type(8))) short bf16x8;

// swizzled row-major LDS index (elem units); XOR bits 3-5 spread rows over banks
#define SWZ64(r,c)  ((((r)*64)  + (c)) ^ (((r)&7)<<3))
#define SWZ128(r,c) ((((r)*128) + (c)) ^ (((r)&7)<<3))

__device__ __forceinline__ float b2f(bf16_t u) {
    union { unsigned int i; float f; } w; w.i = ((unsigned int)u) << 16; return w.f;
}
__device__ __forceinline__ bf16_t f2b(float f) {
    unsigned int x = __float_as_uint(f);
    return (bf16_t)((x + 0x7FFFu + ((x >> 16) & 1u)) >> 16);   // RNE
}
__device__ __forceinline__ void store4b(bf16_t* dst, float4 v) {
    ushort4 u; u.x = f2b(v.x); u.y = f2b(v.y); u.z = f2b(v.z); u.w = f2b(v.w);
    *reinterpret_cast<ushort4*>(dst) = u;
}

__device__ __forceinline__ void gload_lds16(const bf16_t* g, bf16_t* l) {
    __builtin_amdgcn_global_load_lds((const __attribute__((address_space(1))) void*)g,
                                     (__attribute__((address_space(3))) void*)l,
                                     16, 0, 0);
}

// ---------------------------------------------------------------------------
// fused fp32 -> bf16 convert for 3 segments (u, W_in, W_out) in one dispatch
// ---------------------------------------------------------------------------
__global__ __launch_bounds__(256) void f2b3_kernel(const float* __restrict__ a0, bf16_t* __restrict__ o0, long n0,
                                                   const float* __restrict__ a1, bf16_t* __restrict__ o1, long n1,
                                                   const float* __restrict__ a2, bf16_t* __restrict__ o2, long n2)
{
    long i = ((long)blockIdx.x * 256 + threadIdx.x) * 4;
    const float* in; bf16_t* out;
    if (i < n0)            { in = a0 + i; out = o0 + i; }
    else if (i < n0 + n1)  { i -= n0; in = a1 + i; out = o1 + i; }
    else if (i < n0 + n1 + n2) { i -= n0 + n1; in = a2 + i; out = o2 + i; }
    else return;
    float4 v = *reinterpret_cast<const float4*>(in);
    ushort4 o;
    o.x = f2b(v.x); o.y = f2b(v.y); o.z = f2b(v.z); o.w = f2b(v.w);
    *reinterpret_cast<ushort4*>(out) = o;
}

// ---------------------------------------------------------------------------
// 256x256 bf16 MFMA NT-GEMM, K-half counted-vmcnt pipeline, 2 barriers/tile
// (cohesion barriers removed -- all buffer hazards still protected by the
// stage -> counted-vmcnt -> barrier pairs; see R12 analysis).
// ---------------------------------------------------------------------------
template<int NTB, int K, bool OBF16>
__global__ __launch_bounds__(512, 2) void gemm256(const bf16_t* __restrict__ A,
                                                  const bf16_t* __restrict__ B,
                                                  void* __restrict__ Cv,
                                                  long ldc)
{
    constexpr int BK = 64;
    constexpr int NT = K / BK;
    __shared__ bf16_t As[2][2][8192];   // [buf][kh][1024 slots * 8 elems]
    __shared__ bf16_t Bs[2][2][8192];

    const int nwg = gridDim.x;
    const int bid = blockIdx.x;
    const int wg  = ((nwg & 7) == 0) ? ((bid & 7) * (nwg >> 3) + (bid >> 3)) : bid;
    const int bm = (wg / NTB) * 256;
    const int bn = (wg % NTB) * 256;

    const int tid  = threadIdx.x;
    const int lane = tid & 63;
    const int wv   = tid >> 6;
    const int wr   = wv >> 2, wc = wv & 3;       // 2x4 wave grid
    const int l15  = lane & 15, l4 = lane >> 4;

    f32x4 acc[8][4];
    #pragma unroll
    for (int i = 0; i < 8; ++i)
        #pragma unroll
        for (int j = 0; j < 4; ++j) acc[i][j] = (f32x4){0.f, 0.f, 0.f, 0.f};

    const bf16_t* Abase = A + (long)bm * K;
    const bf16_t* Bbase = B + (long)bn * K;

    auto stage_half = [&](int t, int buf, int kh) {
        #pragma unroll
        for (int it = 0; it < 2; ++it) {
            const int s   = it * 512 + tid;          // 0..1023
            const int row = s >> 2;                  // 0..255
            const int jp  = s & 3;                   // physical chunk in half
            const int jl  = jp ^ ((row >> 1) & 3);   // logical chunk in half
            const long go = (long)row * K + t * BK + kh * 32 + jl * 8;
            gload_lds16(Abase + go, &As[buf][kh][s * 8]);
            gload_lds16(Bbase + go, &Bs[buf][kh][s * 8]);
        }
    };
    auto rdA = [&](int buf, int kh, int row) {
        const int jp = l4 ^ ((row >> 1) & 3);
        return *reinterpret_cast<const bf16x8*>(&As[buf][kh][(row * 4 + jp) * 8]);
    };
    auto rdB = [&](int buf, int kh, int row) {
        const int jp = l4 ^ ((row >> 1) & 3);
        return *reinterpret_cast<const bf16x8*>(&Bs[buf][kh][(row * 4 + jp) * 8]);
    };

    stage_half(0, 0, 0);
    stage_half(0, 0, 1);
    asm volatile("s_waitcnt vmcnt(4)" ::: "memory");   // K-half0 of tile 0 landed
    __builtin_amdgcn_s_barrier();

    for (int t = 0; t < NT; ++t) {
        const int cur = t & 1;
        bf16x8 bfr[4], af[4];
        if (t + 1 < NT) stage_half(t + 1, cur ^ 1, 0);
        // K-half 0: qm=0 then qm=1 (no cohesion barrier between)
        #pragma unroll
        for (int ni = 0; ni < 4; ++ni) bfr[ni] = rdB(cur, 0, wc * 64 + ni * 16 + l15);
        #pragma unroll
        for (int mi = 0; mi < 4; ++mi) af[mi] = rdA(cur, 0, wr * 128 + mi * 16 + l15);
        __builtin_amdgcn_s_setprio(1);
        #pragma unroll
        for (int mi = 0; mi < 4; ++mi)
            #pragma unroll
            for (int ni = 0; ni < 4; ++ni)
                acc[mi][ni] = __builtin_amdgcn_mfma_f32_16x16x32_bf16(
                    af[mi], bfr[ni], acc[mi][ni], 0, 0, 0);
        __builtin_amdgcn_s_setprio(0);
        #pragma unroll
        for (int mi = 0; mi < 4; ++mi) af[mi] = rdA(cur, 0, wr * 128 + 64 + mi * 16 + l15);
        __builtin_amdgcn_s_setprio(1);
        #pragma unroll
        for (int mi = 0; mi < 4; ++mi)
            #pragma unroll
            for (int ni = 0; ni < 4; ++ni)
                acc[4 + mi][ni] = __builtin_amdgcn_mfma_f32_16x16x32_bf16(
                    af[mi], bfr[ni], acc[4 + mi][ni], 0, 0, 0);
        __builtin_amdgcn_s_setprio(0);
        if (t + 1 < NT) {
            stage_half(t + 1, cur ^ 1, 1);
            asm volatile("s_waitcnt vmcnt(8)" ::: "memory");   // K1(t) landed
        } else {
            asm volatile("s_waitcnt vmcnt(0)" ::: "memory");
        }
        __builtin_amdgcn_s_barrier();
        // K-half 1: qm=0 then qm=1
        #pragma unroll
        for (int ni = 0; ni < 4; ++ni) bfr[ni] = rdB(cur, 1, wc * 64 + ni * 16 + l15);
        #pragma unroll
        for (int mi = 0; mi < 4; ++mi) af[mi] = rdA(cur, 1, wr * 128 + mi * 16 + l15);
        __builtin_amdgcn_s_setprio(1);
        #pragma unroll
        for (int mi = 0; mi < 4; ++mi)
            #pragma unroll
            for (int ni = 0; ni < 4; ++ni)
                acc[mi][ni] = __builtin_amdgcn_mfma_f32_16x16x32_bf16(
                    af[mi], bfr[ni], acc[mi][ni], 0, 0, 0);
        __builtin_amdgcn_s_setprio(0);
        #pragma unroll
        for (int mi = 0; mi < 4; ++mi) af[mi] = rdA(cur, 1, wr * 128 + 64 + mi * 16 + l15);
        __builtin_amdgcn_s_setprio(1);
        #pragma unroll
        for (int mi = 0; mi < 4; ++mi)
            #pragma unroll
            for (int ni = 0; ni < 4; ++ni)
                acc[4 + mi][ni] = __builtin_amdgcn_mfma_f32_16x16x32_bf16(
                    af[mi], bfr[ni], acc[4 + mi][ni], 0, 0, 0);
        __builtin_amdgcn_s_setprio(0);
        if (t + 1 < NT) { asm volatile("s_waitcnt vmcnt(4)" ::: "memory"); }
        __builtin_amdgcn_s_barrier();
    }

    #pragma unroll
    for (int mf = 0; mf < 8; ++mf) {
        const long grow0 = bm + wr * 128 + mf * 16 + l4 * 4;
        #pragma unroll
        for (int ni = 0; ni < 4; ++ni) {
            const int gcol = bn + wc * 64 + ni * 16 + l15;
            #pragma unroll
            for (int j = 0; j < 4; ++j) {
                if (OBF16)
                    ((bf16_t*)Cv)[(grow0 + j) * ldc + gcol] = f2b(acc[mf][ni][j]);
                else
                    ((float*)Cv)[(grow0 + j) * ldc + gcol] = acc[mf][ni][j];
            }
        }
    }
}

// ---------------------------------------------------------------------------
// 128x128 m97-style MFMA GEMM (A_log 32-col tail), ldc-param.
// ---------------------------------------------------------------------------
template<int N, int K, bool OBF16>
__global__ __launch_bounds__(256) void gemm_mfma(const bf16_t* __restrict__ A,
                                                 const bf16_t* __restrict__ B,
                                                 void* __restrict__ Cv,
                                                 long ldc)
{
    constexpr int BM = 128, BN = 128, BK = 64;
    constexpr int NTB = (N + BN - 1) / BN;
    __shared__ bf16_t As[BM * BK];
    __shared__ bf16_t Bs[BM * BK];

    const int nwg = gridDim.x;
    const int bid = blockIdx.x;
    const int wg  = ((nwg & 7) == 0) ? ((bid & 7) * (nwg >> 3) + (bid >> 3)) : bid;
    const int bm = (wg / NTB) * BM;
    const int bn = (wg % NTB) * BN;

    const int tid  = threadIdx.x;
    const int lane = tid & 63;
    const int wv   = tid >> 6;
    const int wr   = wv >> 1, wc = wv & 1;

    f32x4 acc[4][4];
    #pragma unroll
    for (int i = 0; i < 4; ++i)
        #pragma unroll
        for (int j = 0; j < 4; ++j) acc[i][j] = (f32x4){0.f, 0.f, 0.f, 0.f};

    for (int k0 = 0; k0 < K; k0 += BK) {
        #pragma unroll
        for (int it = 0; it < 4; ++it) {
            const int seg = it * 256 + tid;
            const int row = seg >> 3, c16 = seg & 7;
            gload_lds16(A + (long)(bm + row) * K + k0 + c16 * 8,
                        &As[row * BK + c16 * 8]);
            int brow = bn + row;
            if constexpr (N % BN != 0) brow = min(brow, N - 1);
            gload_lds16(B + (long)brow * K + k0 + c16 * 8,
                        &Bs[row * BK + c16 * 8]);
        }
        __syncthreads();
        #pragma unroll
        for (int kk = 0; kk < 2; ++kk) {
            bf16x8 af[4], bfr[4];
            const int kc = kk * 32 + (lane >> 4) * 8;
            #pragma unroll
            for (int mi = 0; mi < 4; ++mi) {
                const int row = wr * 64 + mi * 16 + (lane & 15);
                af[mi] = *reinterpret_cast<const bf16x8*>(&As[row * BK + kc]);
            }
            #pragma unroll
            for (int ni = 0; ni < 4; ++ni) {
                const int row = wc * 64 + ni * 16 + (lane & 15);
                bfr[ni] = *reinterpret_cast<const bf16x8*>(&Bs[row * BK + kc]);
            }
            #pragma unroll
            for (int mi = 0; mi < 4; ++mi)
                #pragma unroll
                for (int ni = 0; ni < 4; ++ni)
                    acc[mi][ni] = __builtin_amdgcn_mfma_f32_16x16x32_bf16(
                        af[mi], bfr[ni], acc[mi][ni], 0, 0, 0);
        }
        __syncthreads();
    }

    #pragma unroll
    for (int mi = 0; mi < 4; ++mi) {
        const long row0 = bm + wr * 64 + mi * 16 + ((lane >> 4) << 2);
        #pragma unroll
        for (int ni = 0; ni < 4; ++ni) {
            const int col = bn + wc * 64 + ni * 16 + (lane & 15);
            if (N % BN != 0 && col >= N) continue;
            #pragma unroll
            for (int j = 0; j < 4; ++j) {
                if (OBF16)
                    ((bf16_t*)Cv)[(row0 + j) * ldc + col] = f2b(acc[mi][ni][j]);
                else
                    ((float*)Cv)[(row0 + j) * ldc + col] = acc[mi][ni][j];
            }
        }
    }
}

// ---------------------------------------------------------------------------
// Fused causal depthwise conv (K=4), 4 consecutive columns, reading bf16 xBCzA.
// ---------------------------------------------------------------------------
__device__ __forceinline__ float4 conv4v(const bf16_t* __restrict__ xb, long m, int l,
                                         int col, const float* __restrict__ cw,
                                         const float* __restrict__ cbv)
{
    float4 acc = *reinterpret_cast<const float4*>(cbv + col);
    float4 wc0 = *reinterpret_cast<const float4*>(cw + (long)col * 4);
    float4 wc1 = *reinterpret_cast<const float4*>(cw + (long)col * 4 + 4);
    float4 wc2 = *reinterpret_cast<const float4*>(cw + (long)col * 4 + 8);
    float4 wc3 = *reinterpret_cast<const float4*>(cw + (long)col * 4 + 12);
    const float t0[4] = {wc0.x, wc0.y, wc0.z, wc0.w};
    const float t1[4] = {wc1.x, wc1.y, wc1.z, wc1.w};
    const float t2[4] = {wc2.x, wc2.y, wc2.z, wc2.w};
    const float t3[4] = {wc3.x, wc3.y, wc3.z, wc3.w};
    #pragma unroll
    for (int tap = 0; tap < 4; ++tap) {
        if (l - 3 + tap < 0) continue;
        const bf16_t* p = xb + (m - 3 + tap) * (long)IN_OUT + col;
        ushort4 v = *reinterpret_cast<const ushort4*>(p);
        acc.x = fmaf(b2f(v.x), t0[tap], acc.x);
        acc.y = fmaf(b2f(v.y), t1[tap], acc.y);
        acc.z = fmaf(b2f(v.z), t2[tap], acc.z);
        acc.w = fmaf(b2f(v.w), t3[tap], acc.w);
    }
    return acc;
}

// ---------------------------------------------------------------------------
// Phase A (MFMA): dt=softplus (self), wave-shuffle cumsum, states via MFMA.
// EXP: additionally export conv'd B (SWZ64-phys) and x^T (SWZ128-phys).
// ---------------------------------------------------------------------------
template<bool EXP>
__global__ __launch_bounds__(256) void ssd_states(const bf16_t* __restrict__ xb,
                                                  const float* __restrict__ cw,
                                                  const float* __restrict__ cbv,
                                                  bf16_t* __restrict__ states,
                                                  float* __restrict__ cumbuf,
                                                  float* __restrict__ cdecay,
                                                  bf16_t* __restrict__ xtg,
                                                  bf16_t* __restrict__ bg)
{
    const int h = blockIdx.x, c = blockIdx.y, b = blockIdx.z;
    __shared__ bf16_t sx [128 * 64];
    __shared__ bf16_t sBr[128 * 64];
    __shared__ bf16_t sXT[64 * 128];
    __shared__ bf16_t sBT[64 * 128];
    __shared__ float  cum[CHUNK];
    __shared__ float  w0tot;
    const int t = threadIdx.x;
    const long mbase = (long)b * SEQ + (long)c * CHUNK;
    const long cb = ((long)b * NCHUNK + c) * N_QK + h;

    // softplus + wave-level inclusive scan (6 shfl steps, no barriers)
    float v = 0.f;
    if (t < CHUNK) {
        const float a = b2f(xb[(mbase + t) * (long)IN_OUT + (CONV_DIM + D_INNER) + h]);
        v = -((a > 20.f) ? a : log1pf(expf(a)));
        #pragma unroll
        for (int s = 1; s < 64; s <<= 1) {
            const float u2 = __shfl_up(v, s, 64);
            if ((t & 63) >= s) v += u2;
        }
        if (t == 63) w0tot = v;
    }
    for (int idx = t; idx < CHUNK * 16; idx += 256) {
        const int k = idx >> 4, q4 = (idx & 15) * 4;
        const long m = mbase + k;
        const int l = (int)(m & (SEQ - 1));
        float4 xv = conv4v(xb, m, l, h * 64 + q4, cw, cbv);
        float4 bv = conv4v(xb, m, l, D_INNER + h * 64 + q4, cw, cbv);
        store4b(&sx [SWZ64(k, q4)], xv);
        store4b(&sBr[SWZ64(k, q4)], bv);
    }
    __syncthreads();
    if (t >= 64 && t < CHUNK) v += w0tot;
    if (t < CHUNK) cum[t] = v;
    __syncthreads();
    const float clast = cum[CHUNK - 1];
    // transpose x -> sXT; B*decay -> sBT
    {
        const int j = t & 127;
        const int c8b = (t >> 7) * 4;
        const float ej = __expf(clast - cum[j]);
        #pragma unroll
        for (int it = 0; it < 4; ++it) {
            const int c8 = c8b + it;
            bf16x8 xv = *reinterpret_cast<const bf16x8*>(&sx [SWZ64(j, c8 * 8)]);
            bf16x8 bv = *reinterpret_cast<const bf16x8*>(&sBr[SWZ64(j, c8 * 8)]);
            #pragma unroll
            for (int e = 0; e < 8; ++e) {
                sXT[SWZ128(c8 * 8 + e, j)] = xv[e];
                sBT[SWZ128(c8 * 8 + e, j)] = f2b(b2f((bf16_t)bv[e]) * ej);
            }
        }
    }
    __syncthreads();

    const int lane = t & 63, wv = t >> 6;
    const int l15 = lane & 15, l4 = lane >> 4;
    f32x4 acc[4];
    #pragma unroll
    for (int nj = 0; nj < 4; ++nj) acc[nj] = (f32x4){0.f, 0.f, 0.f, 0.f};
    #pragma unroll
    for (int ks = 0; ks < 4; ++ks) {
        const int kc = ks * 32 + l4 * 8;
        bf16x8 af = *reinterpret_cast<const bf16x8*>(&sXT[SWZ128(wv * 16 + l15, kc)]);
        #pragma unroll
        for (int nj = 0; nj < 4; ++nj) {
            bf16x8 bf = *reinterpret_cast<const bf16x8*>(&sBT[SWZ128(nj * 16 + l15, kc)]);
            acc[nj] = __builtin_amdgcn_mfma_f32_16x16x32_bf16(af, bf, acc[nj], 0, 0, 0);
        }
    }
    // write bf16, SWZ64-physical within the 4096-elem block
    #pragma unroll
    for (int nj = 0; nj < 4; ++nj) {
        #pragma unroll
        for (int jj = 0; jj < 4; ++jj) {
            const int p = wv * 16 + l4 * 4 + jj;
            states[cb * 4096 + SWZ64(p, nj * 16 + l15)] = f2b(acc[nj][jj]);
        }
    }
    if constexpr (EXP) {
        #pragma unroll
        for (int it = 0; it < 4; ++it) {
            const int s = it * 256 + t;   // 1024 slots of 8 elems
            *reinterpret_cast<bf16x8*>(xtg + cb * 8192 + s * 8) =
                *reinterpret_cast<const bf16x8*>(&sXT[s * 8]);
            *reinterpret_cast<bf16x8*>(bg + cb * 8192 + s * 8) =
                *reinterpret_cast<const bf16x8*>(&sBr[s * 8]);
        }
    }
    if (t < CHUNK) cumbuf[cb * CHUNK + t] = cum[t];
    if (t == 0)   cdecay[cb] = __expf(clast);
}

// ---------------------------------------------------------------------------
// Phase B: inter-chunk scan, LDS-staged. One block per (b,h,quarter):
// stage all 32 chunk-slices (64KB) at full BW, scan in LDS, write back.
// Replaces the serial 32 x ~900cy HBM pointer-chase.
// ---------------------------------------------------------------------------
__global__ __launch_bounds__(256) void ssd_scan(bf16_t* __restrict__ states,
                                                const float* __restrict__ cdecay)
{
    const int bid = blockIdx.x;
    const int bh = bid >> 2, q = bid & 3;
    const int b = bh >> 5, h = bh & 31;
    const int t = threadIdx.x;
    __shared__ bf16_t sst[NCHUNK * 1024];   // 64 KiB
    __shared__ float  scd[NCHUNK];
    if (t < NCHUNK) scd[t] = cdecay[((long)b * NCHUNK + t) * N_QK + h];
    #pragma unroll
    for (int it = 0; it < 16; ++it) {
        const int slot = it * 256 + t;          // 4096 slots x 16B
        const int c = slot >> 7, off = (slot & 127) * 8;
        const long g = (((long)b * NCHUNK + c) * N_QK + h) * 4096 + q * 1024 + off;
        gload_lds16(states + g, &sst[slot * 8]);
    }
    __syncthreads();   // drains vmcnt (compiler-inserted) + lgkm
    float4 carry = make_float4(0.f, 0.f, 0.f, 0.f);
    for (int c = 0; c < NCHUNK; ++c) {
        ushort4* p = reinterpret_cast<ushort4*>(&sst[c * 1024 + t * 4]);
        const ushort4 su = *p;
        ushort4 pv;
        pv.x = f2b(carry.x); pv.y = f2b(carry.y);
        pv.z = f2b(carry.z); pv.w = f2b(carry.w);
        *p = pv;
        const float cd = scd[c];
        carry.x = fmaf(carry.x, cd, b2f(su.x));
        carry.y = fmaf(carry.y, cd, b2f(su.y));
        carry.z = fmaf(carry.z, cd, b2f(su.z));
        carry.w = fmaf(carry.w, cd, b2f(su.w));
    }
    __syncthreads();
    #pragma unroll
    for (int it = 0; it < 16; ++it) {
        const int slot = it * 256 + t;
        const int c = slot >> 7, off = (slot & 127) * 8;
        const long g = (((long)b * NCHUNK + c) * N_QK + h) * 4096 + q * 1024 + off;
        *reinterpret_cast<bf16x8*>(states + g) =
            *reinterpret_cast<const bf16x8*>(&sst[slot * 8]);
    }
}

// ---------------------------------------------------------------------------
// Phase C (MFMA): S=C·B^T (tri+decay) -> Q bf16 -> y = Q·x + e·(C·prev^T) + D·x
// gate silu(z+zb) -> yz bf16. EXP: x^T and B staged by direct global_load_lds.
// ---------------------------------------------------------------------------
template<bool EXP>
__global__ __launch_bounds__(256) void ssd_out(const bf16_t* __restrict__ xb,
                                               const float* __restrict__ cumbuf,
                                               const bf16_t* __restrict__ prevst,
                                               const float* __restrict__ Dvec,
                                               const float* __restrict__ zbias,
                                               const float* __restrict__ cw,
                                               const float* __restrict__ cbv,
                                               const bf16_t* __restrict__ xtg,
                                               const bf16_t* __restrict__ bg,
                                               bf16_t* __restrict__ yz)
{
    const int h = blockIdx.x, c = blockIdx.y, b = blockIdx.z;
    __shared__ bf16_t sC[128 * 64];
    __shared__ bf16_t sB[128 * 64];
    __shared__ bf16_t sXQ[128 * 64];   // x tile (FB) / Q scratch
    __shared__ bf16_t sXT[64 * 128];   // x^T
    __shared__ bf16_t sP[64 * 64];     // prev state (bf16, SWZ64-physical)
    __shared__ float  cum[CHUNK];
    const int t = threadIdx.x;
    const long mbase = (long)b * SEQ + (long)c * CHUNK;
    const long cb = ((long)b * NCHUNK + c) * N_QK + h;
    if (t < CHUNK) cum[t] = cumbuf[cb * CHUNK + t];
    // prev: direct linear copy (global already SWZ64-physical)
    #pragma unroll
    for (int it = 0; it < 2; ++it) {
        const int s = it * 256 + t;             // 512 slots of 16B
        gload_lds16(prevst + cb * 4096 + s * 8, &sP[s * 8]);
    }
    if constexpr (EXP) {
        #pragma unroll
        for (int it = 0; it < 4; ++it) {
            const int s = it * 256 + t;         // 1024 slots of 16B each
            gload_lds16(bg  + cb * 8192 + s * 8, &sB [s * 8]);
            gload_lds16(xtg + cb * 8192 + s * 8, &sXT[s * 8]);
        }
        for (int idx = t; idx < CHUNK * 16; idx += 256) {
            const int k = idx >> 4, q4 = (idx & 15) * 4;
            const long m = mbase + k;
            const int l = (int)(m & (SEQ - 1));
            float4 cv = conv4v(xb, m, l, 2 * D_INNER + h * 64 + q4, cw, cbv);
            store4b(&sC[SWZ64(k, q4)], cv);
        }
        __syncthreads();   // drains vmcnt+lgkmcnt (compiler-inserted)
    } else {
        for (int idx = t; idx < CHUNK * 16; idx += 256) {
            const int k = idx >> 4, q4 = (idx & 15) * 4;
            const long m = mbase + k;
            const int l = (int)(m & (SEQ - 1));
            float4 xv = conv4v(xb, m, l, h * 64 + q4, cw, cbv);
            float4 bv = conv4v(xb, m, l, D_INNER + h * 64 + q4, cw, cbv);
            float4 cv = conv4v(xb, m, l, 2 * D_INNER + h * 64 + q4, cw, cbv);
            store4b(&sXQ[SWZ64(k, q4)], xv);
            store4b(&sB [SWZ64(k, q4)], bv);
            store4b(&sC [SWZ64(k, q4)], cv);
        }
        __syncthreads();
        {
            const int j = t & 127;
            const int c8b = (t >> 7) * 4;
            #pragma unroll
            for (int it = 0; it < 4; ++it) {
                const int c8 = c8b + it;
                bf16x8 v = *reinterpret_cast<const bf16x8*>(&sXQ[SWZ64(j, c8 * 8)]);
                #pragma unroll
                for (int e = 0; e < 8; ++e) sXT[SWZ128(c8 * 8 + e, j)] = v[e];
            }
        }
        __syncthreads();   // sXQ now dead as x; becomes wave-private Q
    }

    const int lane = t & 63, wv = t >> 6;
    const int w32 = wv * 32, l15 = lane & 15, l4 = lane >> 4;
    bf16_t* sQ = sXQ;

    f32x4 yac[2][4], iac[2][4];
    #pragma unroll
    for (int mi = 0; mi < 2; ++mi)
        #pragma unroll
        for (int np = 0; np < 4; ++np) {
            yac[mi][np] = (f32x4){0.f, 0.f, 0.f, 0.f};
            iac[mi][np] = (f32x4){0.f, 0.f, 0.f, 0.f};
        }

    #pragma unroll
    for (int H = 0; H < 2; ++H) {
        if (H == 1 && wv < 2) break;
        const int j0 = H * 64;
        f32x4 sac[2][4];
        #pragma unroll
        for (int mi = 0; mi < 2; ++mi)
            #pragma unroll
            for (int nj = 0; nj < 4; ++nj) sac[mi][nj] = (f32x4){0.f, 0.f, 0.f, 0.f};
        #pragma unroll
        for (int kk = 0; kk < 2; ++kk) {
            const int kc = kk * 32 + l4 * 8;
            bf16x8 af0 = *reinterpret_cast<const bf16x8*>(&sC[SWZ64(w32 + l15, kc)]);
            bf16x8 af1 = *reinterpret_cast<const bf16x8*>(&sC[SWZ64(w32 + 16 + l15, kc)]);
            #pragma unroll
            for (int nj = 0; nj < 4; ++nj) {
                bf16x8 bfj = *reinterpret_cast<const bf16x8*>(&sB[SWZ64(j0 + nj * 16 + l15, kc)]);
                if (j0 + nj * 16 <= w32 + 15)
                    sac[0][nj] = __builtin_amdgcn_mfma_f32_16x16x32_bf16(af0, bfj, sac[0][nj], 0, 0, 0);
                if (j0 + nj * 16 <= w32 + 31)
                    sac[1][nj] = __builtin_amdgcn_mfma_f32_16x16x32_bf16(af1, bfj, sac[1][nj], 0, 0, 0);
            }
        }
        #pragma unroll
        for (int mi = 0; mi < 2; ++mi) {
            #pragma unroll
            for (int nj = 0; nj < 4; ++nj) {
                const int jcol = nj * 16 + l15;
                const int jg = j0 + jcol;
                #pragma unroll
                for (int jj = 0; jj < 4; ++jj) {
                    const int i = w32 + mi * 16 + l4 * 4 + jj;
                    const float q = (jg <= i) ? __expf(cum[i] - cum[jg]) * sac[mi][nj][jj] : 0.f;
                    sQ[SWZ64(i, jcol)] = f2b(q);
                }
            }
        }
        #pragma unroll
        for (int kk = 0; kk < 2; ++kk) {
            const int kc = kk * 32 + l4 * 8;
            bf16x8 qa0 = *reinterpret_cast<const bf16x8*>(&sQ[SWZ64(w32 + l15, kc)]);
            bf16x8 qa1 = *reinterpret_cast<const bf16x8*>(&sQ[SWZ64(w32 + 16 + l15, kc)]);
            #pragma unroll
            for (int np = 0; np < 4; ++np) {
                bf16x8 xf = *reinterpret_cast<const bf16x8*>(&sXT[SWZ128(np * 16 + l15, j0 + kc)]);
                yac[0][np] = __builtin_amdgcn_mfma_f32_16x16x32_bf16(qa0, xf, yac[0][np], 0, 0, 0);
                yac[1][np] = __builtin_amdgcn_mfma_f32_16x16x32_bf16(qa1, xf, yac[1][np], 0, 0, 0);
            }
        }
    }
    #pragma unroll
    for (int kk = 0; kk < 2; ++kk) {
        const int kc = kk * 32 + l4 * 8;
        bf16x8 cf0 = *reinterpret_cast<const bf16x8*>(&sC[SWZ64(w32 + l15, kc)]);
        bf16x8 cf1 = *reinterpret_cast<const bf16x8*>(&sC[SWZ64(w32 + 16 + l15, kc)]);
        #pragma unroll
        for (int np = 0; np < 4; ++np) {
            bf16x8 pf = *reinterpret_cast<const bf16x8*>(&sP[SWZ64(np * 16 + l15, kc)]);
            iac[0][np] = __builtin_amdgcn_mfma_f32_16x16x32_bf16(cf0, pf, iac[0][np], 0, 0, 0);
            iac[1][np] = __builtin_amdgcn_mfma_f32_16x16x32_bf16(cf1, pf, iac[1][np], 0, 0, 0);
        }
    }
    const float dh = Dvec[h];
    #pragma unroll
    for (int mi = 0; mi < 2; ++mi) {
        #pragma unroll
        for (int jj = 0; jj < 4; ++jj) {
            const int i = w32 + mi * 16 + l4 * 4 + jj;
            const float ei = __expf(cum[i]);
            const long m = mbase + i;
            const bf16_t* zr = xb + m * (long)IN_OUT + CONV_DIM + h * 64;
            bf16_t* orow = yz + m * (long)D_INNER + h * 64;
            #pragma unroll
            for (int np = 0; np < 4; ++np) {
                const int p = np * 16 + l15;
                const float xval = b2f(sXT[SWZ128(p, i)]);
                const float y = yac[mi][np][jj] + ei * iac[mi][np][jj] + dh * xval;
                const float zv = b2f(zr[p]) + zbias[h * 64 + p];
                const float s = zv / (1.f + __expf(-zv));
                orow[p] = f2b(y * s);
            }
        }
    }
}

// ---------------------------------------------------------------------------
extern "C" void kernel_launch(void* const* d_in, const int* in_sizes, int n_in,
                              void* d_out, int out_size, void* d_ws, size_t ws_size,
                              hipStream_t stream)
{
    const float* u      = (const float*)d_in[0];
    const float* W_in   = (const float*)d_in[1];
    const float* conv_w = (const float*)d_in[2];
    const float* conv_b = (const float*)d_in[3];
    const float* Dv     = (const float*)d_in[4];
    const float* z_bias = (const float*)d_in[5];
    const float* W_out  = (const float*)d_in[6];
    float* out = (float*)d_out;

    char* w = (char*)d_ws;
    bf16_t* xbcza = (bf16_t*)w;  w += (long)M_ROWS * IN_OUT * 2;   // 128.5 MiB
    bf16_t* wob   = (bf16_t*)w;  w += (long)2048 * 2048 * 2;       //   8 MiB
    char* ureg = w;  w += 67239936;                                 // 64.1 MiB union
    bf16_t* ub  = (bf16_t*)ureg;                                    // 32 MiB (phase 1)
    bf16_t* wib = (bf16_t*)(ureg + (long)M_ROWS * D_MODEL * 2);     // 32.125 MiB (phase 1)
    bf16_t* yzb = (bf16_t*)ureg;                                    // 32 MiB (phase 2)
    float*  cumb   = (float*)(ureg + (long)M_ROWS * D_INNER * 2);   //  1 MiB
    bf16_t* states = (bf16_t*)(cumb + (long)BATCH * NCHUNK * N_QK * CHUNK); // 16 MiB
    float*  cdec   = (float*)(states + (long)BATCH * NCHUNK * N_QK * 4096); //  8 KiB
    // optional conv-export buffers (64 MiB) -- only if workspace allows
    const long base_bytes = (long)(w - (char*)d_ws);
    const long exp_bytes  = 2L * 2048 * 8192 * 2;                   // xtg + bg
    const bool use_exp = ((long)ws_size >= base_bytes + exp_bytes);
    bf16_t* xtg = (bf16_t*)w;
    bf16_t* bg  = xtg + (long)2048 * 8192;

    // fused fp32->bf16 conversions (u, W_in, W_out)
    {
        const long n0 = (long)M_ROWS * D_MODEL;
        const long n1 = (long)IN_OUT * D_MODEL;
        const long n2 = (long)D_MODEL * D_INNER;
        const long nb = ((n0 + n1 + n2) / 4 + 255) / 256;
        f2b3_kernel<<<(int)nb, 256, 0, stream>>>(u, ub, n0, W_in, wib, n1, W_out, wob, n2);
    }

    // GEMM1 main: cols [0, 8192), 1024 wgs, bm-major
    gemm256<32, D_MODEL, true><<<(M_ROWS / 256) * 32, 512, 0, stream>>>(
        ub, wib, xbcza, IN_OUT);
    // GEMM1 tail: cols [8192, 8224) (A_log)
    gemm_mfma<32, D_MODEL, true><<<(M_ROWS / 128), 256, 0, stream>>>(
        ub, wib + (long)8192 * D_MODEL, xbcza + 8192, IN_OUT);

    if (use_exp) {
        ssd_states<true><<<dim3(N_QK, NCHUNK, BATCH), 256, 0, stream>>>(
            xbcza, conv_w, conv_b, states, cumb, cdec, xtg, bg);
        ssd_scan<<<BATCH * N_QK * 4, 256, 0, stream>>>(states, cdec);
        ssd_out<true><<<dim3(N_QK, NCHUNK, BATCH), 256, 0, stream>>>(
            xbcza, cumb, states, Dv, z_bias, conv_w, conv_b, xtg, bg, yzb);
    } else {
        ssd_states<false><<<dim3(N_QK, NCHUNK, BATCH), 256, 0, stream>>>(
            xbcza, conv_w, conv_b, states, cumb, cdec, nullptr, nullptr);
        ssd_scan<<<BATCH * N_QK * 4, 256, 0, stream>>>(states, cdec);
        ssd_out<false><<<dim3(N_QK, NCHUNK, BATCH), 256, 0, stream>>>(
            xbcza, cumb, states, Dv, z_bias, conv_w, conv_b, nullptr, nullptr, yzb);
    }

    // GEMM2: out = yz @ W_out^T  (8192 x 2048 x 2048), 256 wgs
    gemm256<8, D_INNER, false><<<(M_ROWS / 256) * 8, 512, 0, stream>>>(
        yzb, wob, out, D_MODEL);
}

// Round 13
// 733.406 us; speedup vs baseline: 1.1446x; 1.0985x over previous
//
#include <hip/hip_runtime.h>
#include <math.h>

#define D_MODEL  2048
#define D_INNER  2048
#define N_QK     32
#define N_V      32
#define D_STATE  64
#define D_CONV   4
#define CHUNK    128
#define CONV_DIM 6144      // D_INNER + 2*N_QK*D_STATE
#define IN_OUT   8224      // 2*D_INNER + 2*N_QK*D_STATE + N_V
#define BATCH    2
#define SEQ      4096
#define M_ROWS   (BATCH*SEQ)   // 8192
#define NCHUNK   (SEQ/CHUNK)   // 32

typedef unsigned short bf16_t;
typedef __attribute__((ext_vector_type(4))) float f32x4;
typedef __attribute__((ext_vector_type(8))) short bf16x8;

// swizzled row-major LDS index (elem units); XOR bits 3-5 spread rows over banks
#define SWZ64(r,c)  ((((r)*64)  + (c)) ^ (((r)&7)<<3))
#define SWZ128(r,c) ((((r)*128) + (c)) ^ (((r)&7)<<3))

__device__ __forceinline__ float b2f(bf16_t u) {
    union { unsigned int i; float f; } w; w.i = ((unsigned int)u) << 16; return w.f;
}
__device__ __forceinline__ bf16_t f2b(float f) {
    unsigned int x = __float_as_uint(f);
    return (bf16_t)((x + 0x7FFFu + ((x >> 16) & 1u)) >> 16);   // RNE
}
__device__ __forceinline__ void store4b(bf16_t* dst, float4 v) {
    ushort4 u; u.x = f2b(v.x); u.y = f2b(v.y); u.z = f2b(v.z); u.w = f2b(v.w);
    *reinterpret_cast<ushort4*>(dst) = u;
}

__device__ __forceinline__ void gload_lds16(const bf16_t* g, bf16_t* l) {
    __builtin_amdgcn_global_load_lds((const __attribute__((address_space(1))) void*)g,
                                     (__attribute__((address_space(3))) void*)l,
                                     16, 0, 0);
}

// ---------------------------------------------------------------------------
// fused fp32 -> bf16 convert for 3 segments (u, W_in, W_out) in one dispatch
// ---------------------------------------------------------------------------
__global__ __launch_bounds__(256) void f2b3_kernel(const float* __restrict__ a0, bf16_t* __restrict__ o0, long n0,
                                                   const float* __restrict__ a1, bf16_t* __restrict__ o1, long n1,
                                                   const float* __restrict__ a2, bf16_t* __restrict__ o2, long n2)
{
    long i = ((long)blockIdx.x * 256 + threadIdx.x) * 4;
    const float* in; bf16_t* out;
    if (i < n0)            { in = a0 + i; out = o0 + i; }
    else if (i < n0 + n1)  { i -= n0; in = a1 + i; out = o1 + i; }
    else if (i < n0 + n1 + n2) { i -= n0 + n1; in = a2 + i; out = o2 + i; }
    else return;
    float4 v = *reinterpret_cast<const float4*>(in);
    ushort4 o;
    o.x = f2b(v.x); o.y = f2b(v.y); o.z = f2b(v.z); o.w = f2b(v.w);
    *reinterpret_cast<ushort4*>(out) = o;
}

// ---------------------------------------------------------------------------
// 256x256 bf16 MFMA NT-GEMM, K-half counted-vmcnt pipeline, 2 barriers/tile.
// ---------------------------------------------------------------------------
template<int NTB, int K, bool OBF16>
__global__ __launch_bounds__(512, 2) void gemm256(const bf16_t* __restrict__ A,
                                                  const bf16_t* __restrict__ B,
                                                  void* __restrict__ Cv,
                                                  long ldc)
{
    constexpr int BK = 64;
    constexpr int NT = K / BK;
    __shared__ bf16_t As[2][2][8192];   // [buf][kh][1024 slots * 8 elems]
    __shared__ bf16_t Bs[2][2][8192];

    const int nwg = gridDim.x;
    const int bid = blockIdx.x;
    const int wg  = ((nwg & 7) == 0) ? ((bid & 7) * (nwg >> 3) + (bid >> 3)) : bid;
    const int bm = (wg / NTB) * 256;
    const int bn = (wg % NTB) * 256;

    const int tid  = threadIdx.x;
    const int lane = tid & 63;
    const int wv   = tid >> 6;
    const int wr   = wv >> 2, wc = wv & 3;       // 2x4 wave grid
    const int l15  = lane & 15, l4 = lane >> 4;

    f32x4 acc[8][4];
    #pragma unroll
    for (int i = 0; i < 8; ++i)
        #pragma unroll
        for (int j = 0; j < 4; ++j) acc[i][j] = (f32x4){0.f, 0.f, 0.f, 0.f};

    const bf16_t* Abase = A + (long)bm * K;
    const bf16_t* Bbase = B + (long)bn * K;

    auto stage_half = [&](int t, int buf, int kh) {
        #pragma unroll
        for (int it = 0; it < 2; ++it) {
            const int s   = it * 512 + tid;          // 0..1023
            const int row = s >> 2;                  // 0..255
            const int jp  = s & 3;                   // physical chunk in half
            const int jl  = jp ^ ((row >> 1) & 3);   // logical chunk in half
            const long go = (long)row * K + t * BK + kh * 32 + jl * 8;
            gload_lds16(Abase + go, &As[buf][kh][s * 8]);
            gload_lds16(Bbase + go, &Bs[buf][kh][s * 8]);
        }
    };
    auto rdA = [&](int buf, int kh, int row) {
        const int jp = l4 ^ ((row >> 1) & 3);
        return *reinterpret_cast<const bf16x8*>(&As[buf][kh][(row * 4 + jp) * 8]);
    };
    auto rdB = [&](int buf, int kh, int row) {
        const int jp = l4 ^ ((row >> 1) & 3);
        return *reinterpret_cast<const bf16x8*>(&Bs[buf][kh][(row * 4 + jp) * 8]);
    };

    stage_half(0, 0, 0);
    stage_half(0, 0, 1);
    asm volatile("s_waitcnt vmcnt(4)" ::: "memory");   // K-half0 of tile 0 landed
    __builtin_amdgcn_s_barrier();

    for (int t = 0; t < NT; ++t) {
        const int cur = t & 1;
        bf16x8 bfr[4], af[4];
        if (t + 1 < NT) stage_half(t + 1, cur ^ 1, 0);
        // K-half 0: qm=0 then qm=1
        #pragma unroll
        for (int ni = 0; ni < 4; ++ni) bfr[ni] = rdB(cur, 0, wc * 64 + ni * 16 + l15);
        #pragma unroll
        for (int mi = 0; mi < 4; ++mi) af[mi] = rdA(cur, 0, wr * 128 + mi * 16 + l15);
        __builtin_amdgcn_s_setprio(1);
        #pragma unroll
        for (int mi = 0; mi < 4; ++mi)
            #pragma unroll
            for (int ni = 0; ni < 4; ++ni)
                acc[mi][ni] = __builtin_amdgcn_mfma_f32_16x16x32_bf16(
                    af[mi], bfr[ni], acc[mi][ni], 0, 0, 0);
        __builtin_amdgcn_s_setprio(0);
        #pragma unroll
        for (int mi = 0; mi < 4; ++mi) af[mi] = rdA(cur, 0, wr * 128 + 64 + mi * 16 + l15);
        __builtin_amdgcn_s_setprio(1);
        #pragma unroll
        for (int mi = 0; mi < 4; ++mi)
            #pragma unroll
            for (int ni = 0; ni < 4; ++ni)
                acc[4 + mi][ni] = __builtin_amdgcn_mfma_f32_16x16x32_bf16(
                    af[mi], bfr[ni], acc[4 + mi][ni], 0, 0, 0);
        __builtin_amdgcn_s_setprio(0);
        if (t + 1 < NT) {
            stage_half(t + 1, cur ^ 1, 1);
            asm volatile("s_waitcnt vmcnt(8)" ::: "memory");   // K1(t) landed
        } else {
            asm volatile("s_waitcnt vmcnt(0)" ::: "memory");
        }
        __builtin_amdgcn_s_barrier();
        // K-half 1: qm=0 then qm=1
        #pragma unroll
        for (int ni = 0; ni < 4; ++ni) bfr[ni] = rdB(cur, 1, wc * 64 + ni * 16 + l15);
        #pragma unroll
        for (int mi = 0; mi < 4; ++mi) af[mi] = rdA(cur, 1, wr * 128 + mi * 16 + l15);
        __builtin_amdgcn_s_setprio(1);
        #pragma unroll
        for (int mi = 0; mi < 4; ++mi)
            #pragma unroll
            for (int ni = 0; ni < 4; ++ni)
                acc[mi][ni] = __builtin_amdgcn_mfma_f32_16x16x32_bf16(
                    af[mi], bfr[ni], acc[mi][ni], 0, 0, 0);
        __builtin_amdgcn_s_setprio(0);
        #pragma unroll
        for (int mi = 0; mi < 4; ++mi) af[mi] = rdA(cur, 1, wr * 128 + 64 + mi * 16 + l15);
        __builtin_amdgcn_s_setprio(1);
        #pragma unroll
        for (int mi = 0; mi < 4; ++mi)
            #pragma unroll
            for (int ni = 0; ni < 4; ++ni)
                acc[4 + mi][ni] = __builtin_amdgcn_mfma_f32_16x16x32_bf16(
                    af[mi], bfr[ni], acc[4 + mi][ni], 0, 0, 0);
        __builtin_amdgcn_s_setprio(0);
        if (t + 1 < NT) { asm volatile("s_waitcnt vmcnt(4)" ::: "memory"); }
        __builtin_amdgcn_s_barrier();
    }

    #pragma unroll
    for (int mf = 0; mf < 8; ++mf) {
        const long grow0 = bm + wr * 128 + mf * 16 + l4 * 4;
        #pragma unroll
        for (int ni = 0; ni < 4; ++ni) {
            const int gcol = bn + wc * 64 + ni * 16 + l15;
            #pragma unroll
            for (int j = 0; j < 4; ++j) {
                if (OBF16)
                    ((bf16_t*)Cv)[(grow0 + j) * ldc + gcol] = f2b(acc[mf][ni][j]);
                else
                    ((float*)Cv)[(grow0 + j) * ldc + gcol] = acc[mf][ni][j];
            }
        }
    }
}

// ---------------------------------------------------------------------------
// 128x128 m97-style MFMA GEMM (A_log 32-col tail), ldc-param.
// ---------------------------------------------------------------------------
template<int N, int K, bool OBF16>
__global__ __launch_bounds__(256) void gemm_mfma(const bf16_t* __restrict__ A,
                                                 const bf16_t* __restrict__ B,
                                                 void* __restrict__ Cv,
                                                 long ldc)
{
    constexpr int BM = 128, BN = 128, BK = 64;
    constexpr int NTB = (N + BN - 1) / BN;
    __shared__ bf16_t As[BM * BK];
    __shared__ bf16_t Bs[BM * BK];

    const int nwg = gridDim.x;
    const int bid = blockIdx.x;
    const int wg  = ((nwg & 7) == 0) ? ((bid & 7) * (nwg >> 3) + (bid >> 3)) : bid;
    const int bm = (wg / NTB) * BM;
    const int bn = (wg % NTB) * BN;

    const int tid  = threadIdx.x;
    const int lane = tid & 63;
    const int wv   = tid >> 6;
    const int wr   = wv >> 1, wc = wv & 1;

    f32x4 acc[4][4];
    #pragma unroll
    for (int i = 0; i < 4; ++i)
        #pragma unroll
        for (int j = 0; j < 4; ++j) acc[i][j] = (f32x4){0.f, 0.f, 0.f, 0.f};

    for (int k0 = 0; k0 < K; k0 += BK) {
        #pragma unroll
        for (int it = 0; it < 4; ++it) {
            const int seg = it * 256 + tid;
            const int row = seg >> 3, c16 = seg & 7;
            gload_lds16(A + (long)(bm + row) * K + k0 + c16 * 8,
                        &As[row * BK + c16 * 8]);
            int brow = bn + row;
            if constexpr (N % BN != 0) brow = min(brow, N - 1);
            gload_lds16(B + (long)brow * K + k0 + c16 * 8,
                        &Bs[row * BK + c16 * 8]);
        }
        __syncthreads();
        #pragma unroll
        for (int kk = 0; kk < 2; ++kk) {
            bf16x8 af[4], bfr[4];
            const int kc = kk * 32 + (lane >> 4) * 8;
            #pragma unroll
            for (int mi = 0; mi < 4; ++mi) {
                const int row = wr * 64 + mi * 16 + (lane & 15);
                af[mi] = *reinterpret_cast<const bf16x8*>(&As[row * BK + kc]);
            }
            #pragma unroll
            for (int ni = 0; ni < 4; ++ni) {
                const int row = wc * 64 + ni * 16 + (lane & 15);
                bfr[ni] = *reinterpret_cast<const bf16x8*>(&Bs[row * BK + kc]);
            }
            #pragma unroll
            for (int mi = 0; mi < 4; ++mi)
                #pragma unroll
                for (int ni = 0; ni < 4; ++ni)
                    acc[mi][ni] = __builtin_amdgcn_mfma_f32_16x16x32_bf16(
                        af[mi], bfr[ni], acc[mi][ni], 0, 0, 0);
        }
        __syncthreads();
    }

    #pragma unroll
    for (int mi = 0; mi < 4; ++mi) {
        const long row0 = bm + wr * 64 + mi * 16 + ((lane >> 4) << 2);
        #pragma unroll
        for (int ni = 0; ni < 4; ++ni) {
            const int col = bn + wc * 64 + ni * 16 + (lane & 15);
            if (N % BN != 0 && col >= N) continue;
            #pragma unroll
            for (int j = 0; j < 4; ++j) {
                if (OBF16)
                    ((bf16_t*)Cv)[(row0 + j) * ldc + col] = f2b(acc[mi][ni][j]);
                else
                    ((float*)Cv)[(row0 + j) * ldc + col] = acc[mi][ni][j];
            }
        }
    }
}

// ---------------------------------------------------------------------------
// Fused causal depthwise conv (K=4), 4 consecutive columns, reading bf16 xBCzA.
// ---------------------------------------------------------------------------
__device__ __forceinline__ float4 conv4v(const bf16_t* __restrict__ xb, long m, int l,
                                         int col, const float* __restrict__ cw,
                                         const float* __restrict__ cbv)
{
    float4 acc = *reinterpret_cast<const float4*>(cbv + col);
    float4 wc0 = *reinterpret_cast<const float4*>(cw + (long)col * 4);
    float4 wc1 = *reinterpret_cast<const float4*>(cw + (long)col * 4 + 4);
    float4 wc2 = *reinterpret_cast<const float4*>(cw + (long)col * 4 + 8);
    float4 wc3 = *reinterpret_cast<const float4*>(cw + (long)col * 4 + 12);
    const float t0[4] = {wc0.x, wc0.y, wc0.z, wc0.w};
    const float t1[4] = {wc1.x, wc1.y, wc1.z, wc1.w};
    const float t2[4] = {wc2.x, wc2.y, wc2.z, wc2.w};
    const float t3[4] = {wc3.x, wc3.y, wc3.z, wc3.w};
    #pragma unroll
    for (int tap = 0; tap < 4; ++tap) {
        if (l - 3 + tap < 0) continue;
        const bf16_t* p = xb + (m - 3 + tap) * (long)IN_OUT + col;
        ushort4 v = *reinterpret_cast<const ushort4*>(p);
        acc.x = fmaf(b2f(v.x), t0[tap], acc.x);
        acc.y = fmaf(b2f(v.y), t1[tap], acc.y);
        acc.z = fmaf(b2f(v.z), t2[tap], acc.z);
        acc.w = fmaf(b2f(v.w), t3[tap], acc.w);
    }
    return acc;
}

// ---------------------------------------------------------------------------
// Phase A (MFMA): 512 threads / 8 waves (4 row-groups x 2 col-halves).
// dt=softplus (self), wave-shuffle cumsum, states via MFMA.
// EXP: export conv'd B (SWZ64-phys) and x^T (SWZ128-phys).
// ---------------------------------------------------------------------------
template<bool EXP>
__global__ __launch_bounds__(512, 4) void ssd_states(const bf16_t* __restrict__ xb,
                                                     const float* __restrict__ cw,
                                                     const float* __restrict__ cbv,
                                                     bf16_t* __restrict__ states,
                                                     float* __restrict__ cumbuf,
                                                     float* __restrict__ cdecay,
                                                     bf16_t* __restrict__ xtg,
                                                     bf16_t* __restrict__ bg)
{
    const int h = blockIdx.x, c = blockIdx.y, b = blockIdx.z;
    __shared__ bf16_t sx [128 * 64];
    __shared__ bf16_t sBr[128 * 64];
    __shared__ bf16_t sXT[64 * 128];
    __shared__ bf16_t sBT[64 * 128];
    __shared__ float  cum[CHUNK];
    __shared__ float  w0tot;
    const int t = threadIdx.x;
    const long mbase = (long)b * SEQ + (long)c * CHUNK;
    const long cb = ((long)b * NCHUNK + c) * N_QK + h;

    // softplus + wave-level inclusive scan (6 shfl steps, no barriers)
    float v = 0.f;
    if (t < CHUNK) {
        const float a = b2f(xb[(mbase + t) * (long)IN_OUT + (CONV_DIM + D_INNER) + h]);
        v = -((a > 20.f) ? a : log1pf(expf(a)));
        #pragma unroll
        for (int s = 1; s < 64; s <<= 1) {
            const float u2 = __shfl_up(v, s, 64);
            if ((t & 63) >= s) v += u2;
        }
        if (t == 63) w0tot = v;
    }
    for (int idx = t; idx < CHUNK * 16; idx += 512) {
        const int k = idx >> 4, q4 = (idx & 15) * 4;
        const long m = mbase + k;
        const int l = (int)(m & (SEQ - 1));
        float4 xv = conv4v(xb, m, l, h * 64 + q4, cw, cbv);
        float4 bv = conv4v(xb, m, l, D_INNER + h * 64 + q4, cw, cbv);
        store4b(&sx [SWZ64(k, q4)], xv);
        store4b(&sBr[SWZ64(k, q4)], bv);
    }
    __syncthreads();
    if (t >= 64 && t < CHUNK) v += w0tot;
    if (t < CHUNK) cum[t] = v;
    __syncthreads();
    const float clast = cum[CHUNK - 1];
    // transpose x -> sXT; B*decay -> sBT  (1024 tasks over 512 threads x 2)
    {
        const int j = t & 127;
        const int c8b = (t >> 7) * 2;
        const float ej = __expf(clast - cum[j]);
        #pragma unroll
        for (int it = 0; it < 2; ++it) {
            const int c8 = c8b + it;
            bf16x8 xv = *reinterpret_cast<const bf16x8*>(&sx [SWZ64(j, c8 * 8)]);
            bf16x8 bv = *reinterpret_cast<const bf16x8*>(&sBr[SWZ64(j, c8 * 8)]);
            #pragma unroll
            for (int e = 0; e < 8; ++e) {
                sXT[SWZ128(c8 * 8 + e, j)] = xv[e];
                sBT[SWZ128(c8 * 8 + e, j)] = f2b(b2f((bf16_t)bv[e]) * ej);
            }
        }
    }
    __syncthreads();

    const int lane = t & 63, wv = t >> 6;       // wv 0..7
    const int l15 = lane & 15, l4 = lane >> 4;
    const int prow  = (wv & 3) * 16;            // row group 0..3
    const int nbase = (wv >> 2) * 2;            // col-half base nj (0 or 2)
    f32x4 acc[2];
    acc[0] = (f32x4){0.f, 0.f, 0.f, 0.f};
    acc[1] = (f32x4){0.f, 0.f, 0.f, 0.f};
    #pragma unroll
    for (int ks = 0; ks < 4; ++ks) {
        const int kc = ks * 32 + l4 * 8;
        bf16x8 af = *reinterpret_cast<const bf16x8*>(&sXT[SWZ128(prow + l15, kc)]);
        #pragma unroll
        for (int nj = 0; nj < 2; ++nj) {
            bf16x8 bf = *reinterpret_cast<const bf16x8*>(&sBT[SWZ128((nbase + nj) * 16 + l15, kc)]);
            acc[nj] = __builtin_amdgcn_mfma_f32_16x16x32_bf16(af, bf, acc[nj], 0, 0, 0);
        }
    }
    // write bf16, SWZ64-physical within the 4096-elem block
    #pragma unroll
    for (int nj = 0; nj < 2; ++nj) {
        #pragma unroll
        for (int jj = 0; jj < 4; ++jj) {
            const int p = prow + l4 * 4 + jj;
            states[cb * 4096 + SWZ64(p, (nbase + nj) * 16 + l15)] = f2b(acc[nj][jj]);
        }
    }
    if constexpr (EXP) {
        #pragma unroll
        for (int it = 0; it < 2; ++it) {
            const int s = it * 512 + t;   // 1024 slots of 8 elems
            *reinterpret_cast<bf16x8*>(xtg + cb * 8192 + s * 8) =
                *reinterpret_cast<const bf16x8*>(&sXT[s * 8]);
            *reinterpret_cast<bf16x8*>(bg + cb * 8192 + s * 8) =
                *reinterpret_cast<const bf16x8*>(&sBr[s * 8]);
        }
    }
    if (t < CHUNK) cumbuf[cb * CHUNK + t] = cum[t];
    if (t == 0)   cdecay[cb] = __expf(clast);
}

// ---------------------------------------------------------------------------
// Phase B: inter-chunk scan, LDS-staged (R12-proven).
// ---------------------------------------------------------------------------
__global__ __launch_bounds__(256) void ssd_scan(bf16_t* __restrict__ states,
                                                const float* __restrict__ cdecay)
{
    const int bid = blockIdx.x;
    const int bh = bid >> 2, q = bid & 3;
    const int b = bh >> 5, h = bh & 31;
    const int t = threadIdx.x;
    __shared__ bf16_t sst[NCHUNK * 1024];   // 64 KiB
    __shared__ float  scd[NCHUNK];
    if (t < NCHUNK) scd[t] = cdecay[((long)b * NCHUNK + t) * N_QK + h];
    #pragma unroll
    for (int it = 0; it < 16; ++it) {
        const int slot = it * 256 + t;          // 4096 slots x 16B
        const int c = slot >> 7, off = (slot & 127) * 8;
        const long g = (((long)b * NCHUNK + c) * N_QK + h) * 4096 + q * 1024 + off;
        gload_lds16(states + g, &sst[slot * 8]);
    }
    __syncthreads();
    float4 carry = make_float4(0.f, 0.f, 0.f, 0.f);
    for (int c = 0; c < NCHUNK; ++c) {
        ushort4* p = reinterpret_cast<ushort4*>(&sst[c * 1024 + t * 4]);
        const ushort4 su = *p;
        ushort4 pv;
        pv.x = f2b(carry.x); pv.y = f2b(carry.y);
        pv.z = f2b(carry.z); pv.w = f2b(carry.w);
        *p = pv;
        const float cd = scd[c];
        carry.x = fmaf(carry.x, cd, b2f(su.x));
        carry.y = fmaf(carry.y, cd, b2f(su.y));
        carry.z = fmaf(carry.z, cd, b2f(su.z));
        carry.w = fmaf(carry.w, cd, b2f(su.w));
    }
    __syncthreads();
    #pragma unroll
    for (int it = 0; it < 16; ++it) {
        const int slot = it * 256 + t;
        const int c = slot >> 7, off = (slot & 127) * 8;
        const long g = (((long)b * NCHUNK + c) * N_QK + h) * 4096 + q * 1024 + off;
        *reinterpret_cast<bf16x8*>(states + g) =
            *reinterpret_cast<const bf16x8*>(&sst[slot * 8]);
    }
}

// ---------------------------------------------------------------------------
// Phase C (MFMA): 512 threads / 8 waves, each owning 16 output rows.
// S=C·B^T (tri+decay) -> Q bf16 -> y = Q·x + e·(C·prev^T) + D·x, silu gate.
// EXP: x^T and B staged by direct global_load_lds from ssd_states exports.
// ---------------------------------------------------------------------------
template<bool EXP>
__global__ __launch_bounds__(512, 4) void ssd_out(const bf16_t* __restrict__ xb,
                                                  const float* __restrict__ cumbuf,
                                                  const bf16_t* __restrict__ prevst,
                                                  const float* __restrict__ Dvec,
                                                  const float* __restrict__ zbias,
                                                  const float* __restrict__ cw,
                                                  const float* __restrict__ cbv,
                                                  const bf16_t* __restrict__ xtg,
                                                  const bf16_t* __restrict__ bg,
                                                  bf16_t* __restrict__ yz)
{
    const int h = blockIdx.x, c = blockIdx.y, b = blockIdx.z;
    __shared__ bf16_t sC[128 * 64];
    __shared__ bf16_t sB[128 * 64];
    __shared__ bf16_t sXQ[128 * 64];   // x tile (FB) / Q scratch
    __shared__ bf16_t sXT[64 * 128];   // x^T
    __shared__ bf16_t sP[64 * 64];     // prev state (bf16, SWZ64-physical)
    __shared__ float  cum[CHUNK];
    const int t = threadIdx.x;
    const long mbase = (long)b * SEQ + (long)c * CHUNK;
    const long cb = ((long)b * NCHUNK + c) * N_QK + h;
    if (t < CHUNK) cum[t] = cumbuf[cb * CHUNK + t];
    // prev: 512 slots of 16B, one per thread
    gload_lds16(prevst + cb * 4096 + t * 8, &sP[t * 8]);
    if constexpr (EXP) {
        #pragma unroll
        for (int it = 0; it < 2; ++it) {
            const int s = it * 512 + t;         // 1024 slots of 16B each
            gload_lds16(bg  + cb * 8192 + s * 8, &sB [s * 8]);
            gload_lds16(xtg + cb * 8192 + s * 8, &sXT[s * 8]);
        }
        for (int idx = t; idx < CHUNK * 16; idx += 512) {
            const int k = idx >> 4, q4 = (idx & 15) * 4;
            const long m = mbase + k;
            const int l = (int)(m & (SEQ - 1));
            float4 cv = conv4v(xb, m, l, 2 * D_INNER + h * 64 + q4, cw, cbv);
            store4b(&sC[SWZ64(k, q4)], cv);
        }
        __syncthreads();
    } else {
        for (int idx = t; idx < CHUNK * 16; idx += 512) {
            const int k = idx >> 4, q4 = (idx & 15) * 4;
            const long m = mbase + k;
            const int l = (int)(m & (SEQ - 1));
            float4 xv = conv4v(xb, m, l, h * 64 + q4, cw, cbv);
            float4 bv = conv4v(xb, m, l, D_INNER + h * 64 + q4, cw, cbv);
            float4 cv = conv4v(xb, m, l, 2 * D_INNER + h * 64 + q4, cw, cbv);
            store4b(&sXQ[SWZ64(k, q4)], xv);
            store4b(&sB [SWZ64(k, q4)], bv);
            store4b(&sC [SWZ64(k, q4)], cv);
        }
        __syncthreads();
        {
            const int j = t & 127;
            const int c8b = (t >> 7) * 2;
            #pragma unroll
            for (int it = 0; it < 2; ++it) {
                const int c8 = c8b + it;
                bf16x8 v = *reinterpret_cast<const bf16x8*>(&sXQ[SWZ64(j, c8 * 8)]);
                #pragma unroll
                for (int e = 0; e < 8; ++e) sXT[SWZ128(c8 * 8 + e, j)] = v[e];
            }
        }
        __syncthreads();   // sXQ now dead as x; becomes wave-private Q
    }

    const int lane = t & 63, wv = t >> 6;       // wv 0..7
    const int w16 = wv * 16, l15 = lane & 15, l4 = lane >> 4;
    bf16_t* sQ = sXQ;

    f32x4 yac[4], iac[4];
    #pragma unroll
    for (int np = 0; np < 4; ++np) {
        yac[np] = (f32x4){0.f, 0.f, 0.f, 0.f};
        iac[np] = (f32x4){0.f, 0.f, 0.f, 0.f};
    }

    #pragma unroll
    for (int H = 0; H < 2; ++H) {
        if (H == 1 && wv < 4) break;            // rows <64 have no j>=64 terms
        const int j0 = H * 64;
        f32x4 sac[4];
        #pragma unroll
        for (int nj = 0; nj < 4; ++nj) sac[nj] = (f32x4){0.f, 0.f, 0.f, 0.f};
        #pragma unroll
        for (int kk = 0; kk < 2; ++kk) {
            const int kc = kk * 32 + l4 * 8;
            bf16x8 af0 = *reinterpret_cast<const bf16x8*>(&sC[SWZ64(w16 + l15, kc)]);
            #pragma unroll
            for (int nj = 0; nj < 4; ++nj) {
                if (j0 + nj * 16 <= w16 + 15) {
                    bf16x8 bfj = *reinterpret_cast<const bf16x8*>(&sB[SWZ64(j0 + nj * 16 + l15, kc)]);
                    sac[nj] = __builtin_amdgcn_mfma_f32_16x16x32_bf16(af0, bfj, sac[nj], 0, 0, 0);
                }
            }
        }
        // decay-mask -> bf16 Q (wave-private rows w16..w16+15)
        #pragma unroll
        for (int nj = 0; nj < 4; ++nj) {
            const int jcol = nj * 16 + l15;
            const int jg = j0 + jcol;
            #pragma unroll
            for (int jj = 0; jj < 4; ++jj) {
                const int i = w16 + l4 * 4 + jj;
                const float q = (jg <= i) ? __expf(cum[i] - cum[jg]) * sac[nj][jj] : 0.f;
                sQ[SWZ64(i, jcol)] = f2b(q);
            }
        }
        // y += Q_half · x_half  (same wave wrote these Q rows; lockstep => safe)
        #pragma unroll
        for (int kk = 0; kk < 2; ++kk) {
            const int kc = kk * 32 + l4 * 8;
            bf16x8 qa = *reinterpret_cast<const bf16x8*>(&sQ[SWZ64(w16 + l15, kc)]);
            #pragma unroll
            for (int np = 0; np < 4; ++np) {
                bf16x8 xf = *reinterpret_cast<const bf16x8*>(&sXT[SWZ128(np * 16 + l15, j0 + kc)]);
                yac[np] = __builtin_amdgcn_mfma_f32_16x16x32_bf16(qa, xf, yac[np], 0, 0, 0);
            }
        }
    }
    // y_inter = C · prev^T
    #pragma unroll
    for (int kk = 0; kk < 2; ++kk) {
        const int kc = kk * 32 + l4 * 8;
        bf16x8 cf = *reinterpret_cast<const bf16x8*>(&sC[SWZ64(w16 + l15, kc)]);
        #pragma unroll
        for (int np = 0; np < 4; ++np) {
            bf16x8 pf = *reinterpret_cast<const bf16x8*>(&sP[SWZ64(np * 16 + l15, kc)]);
            iac[np] = __builtin_amdgcn_mfma_f32_16x16x32_bf16(cf, pf, iac[np], 0, 0, 0);
        }
    }
    // writeout: y = y_intra + exp(cum_i)*y_inter + D*x; gate silu(z+zb)
    const float dh = Dvec[h];
    #pragma unroll
    for (int jj = 0; jj < 4; ++jj) {
        const int i = w16 + l4 * 4 + jj;
        const float ei = __expf(cum[i]);
        const long m = mbase + i;
        const bf16_t* zr = xb + m * (long)IN_OUT + CONV_DIM + h * 64;
        bf16_t* orow = yz + m * (long)D_INNER + h * 64;
        #pragma unroll
        for (int np = 0; np < 4; ++np) {
            const int p = np * 16 + l15;
            const float xval = b2f(sXT[SWZ128(p, i)]);
            const float y = yac[np][jj] + ei * iac[np][jj] + dh * xval;
            const float zv = b2f(zr[p]) + zbias[h * 64 + p];
            const float s = zv / (1.f + __expf(-zv));
            orow[p] = f2b(y * s);
        }
    }
}

// ---------------------------------------------------------------------------
extern "C" void kernel_launch(void* const* d_in, const int* in_sizes, int n_in,
                              void* d_out, int out_size, void* d_ws, size_t ws_size,
                              hipStream_t stream)
{
    const float* u      = (const float*)d_in[0];
    const float* W_in   = (const float*)d_in[1];
    const float* conv_w = (const float*)d_in[2];
    const float* conv_b = (const float*)d_in[3];
    const float* Dv     = (const float*)d_in[4];
    const float* z_bias = (const float*)d_in[5];
    const float* W_out  = (const float*)d_in[6];
    float* out = (float*)d_out;

    char* w = (char*)d_ws;
    bf16_t* xbcza = (bf16_t*)w;  w += (long)M_ROWS * IN_OUT * 2;   // 128.5 MiB
    bf16_t* wob   = (bf16_t*)w;  w += (long)2048 * 2048 * 2;       //   8 MiB
    char* ureg = w;  w += 67239936;                                 // 64.1 MiB union
    bf16_t* ub  = (bf16_t*)ureg;                                    // 32 MiB (phase 1)
    bf16_t* wib = (bf16_t*)(ureg + (long)M_ROWS * D_MODEL * 2);     // 32.125 MiB (phase 1)
    bf16_t* yzb = (bf16_t*)ureg;                                    // 32 MiB (phase 2)
    float*  cumb   = (float*)(ureg + (long)M_ROWS * D_INNER * 2);   //  1 MiB
    bf16_t* states = (bf16_t*)(cumb + (long)BATCH * NCHUNK * N_QK * CHUNK); // 16 MiB
    float*  cdec   = (float*)(states + (long)BATCH * NCHUNK * N_QK * 4096); //  8 KiB
    const long base_bytes = (long)(w - (char*)d_ws);
    const long exp_bytes  = 2L * 2048 * 8192 * 2;                   // xtg + bg
    const bool use_exp = ((long)ws_size >= base_bytes + exp_bytes);
    bf16_t* xtg = (bf16_t*)w;
    bf16_t* bg  = xtg + (long)2048 * 8192;

    // fused fp32->bf16 conversions (u, W_in, W_out)
    {
        const long n0 = (long)M_ROWS * D_MODEL;
        const long n1 = (long)IN_OUT * D_MODEL;
        const long n2 = (long)D_MODEL * D_INNER;
        const long nb = ((n0 + n1 + n2) / 4 + 255) / 256;
        f2b3_kernel<<<(int)nb, 256, 0, stream>>>(u, ub, n0, W_in, wib, n1, W_out, wob, n2);
    }

    // GEMM1 main: cols [0, 8192), 1024 wgs, bm-major
    gemm256<32, D_MODEL, true><<<(M_ROWS / 256) * 32, 512, 0, stream>>>(
        ub, wib, xbcza, IN_OUT);
    // GEMM1 tail: cols [8192, 8224) (A_log)
    gemm_mfma<32, D_MODEL, true><<<(M_ROWS / 128), 256, 0, stream>>>(
        ub, wib + (long)8192 * D_MODEL, xbcza + 8192, IN_OUT);

    if (use_exp) {
        ssd_states<true><<<dim3(N_QK, NCHUNK, BATCH), 512, 0, stream>>>(
            xbcza, conv_w, conv_b, states, cumb, cdec, xtg, bg);
        ssd_scan<<<BATCH * N_QK * 4, 256, 0, stream>>>(states, cdec);
        ssd_out<true><<<dim3(N_QK, NCHUNK, BATCH), 512, 0, stream>>>(
            xbcza, cumb, states, Dv, z_bias, conv_w, conv_b, xtg, bg, yzb);
    } else {
        ssd_states<false><<<dim3(N_QK, NCHUNK, BATCH), 512, 0, stream>>>(
            xbcza, conv_w, conv_b, states, cumb, cdec, nullptr, nullptr);
        ssd_scan<<<BATCH * N_QK * 4, 256, 0, stream>>>(states, cdec);
        ssd_out<false><<<dim3(N_QK, NCHUNK, BATCH), 512, 0, stream>>>(
            xbcza, cumb, states, Dv, z_bias, conv_w, conv_b, nullptr, nullptr, yzb);
    }

    // GEMM2: out = yz @ W_out^T  (8192 x 2048 x 2048), 256 wgs
    gemm256<8, D_INNER, false><<<(M_ROWS / 256) * 8, 512, 0, stream>>>(
        yzb, wob, out, D_MODEL);
}